// Round 12
// baseline (929.282 us; speedup 1.0000x reference)
//
#include <hip/hip_runtime.h>

// Shapes (fixed): B=4 S=1024 D=1024 H=16 HD=64 C=64 NC=16 DFF=256
typedef short v8s __attribute__((ext_vector_type(8)));
typedef short v4s __attribute__((ext_vector_type(4)));
typedef float v4f __attribute__((ext_vector_type(4)));

__device__ __forceinline__ float bfu(unsigned short u){ return __uint_as_float(((unsigned)u)<<16); }
__device__ __forceinline__ unsigned short fbf(float f){
  unsigned u = __float_as_uint(f);
  u += 0x7fffu + ((u>>16)&1u);
  return (unsigned short)(u>>16);
}
__device__ __forceinline__ float wsum(float v){
  #pragma unroll
  for (int off=32; off>0; off>>=1) v += __shfl_xor(v, off, 64);
  return v;
}
__device__ __forceinline__ float clampv(float x){ return fminf(fmaxf(x, -1e8f), 1e8f); }
__device__ __forceinline__ float tanh_f(float x){
  x = fminf(fmaxf(x, -15.f), 15.f);
  float e = __expf(2.f*x);
  return (e-1.f)/(e+1.f);
}
__device__ __forceinline__ float gelu_f(float x){
  float t = tanh_f(0.79788456f*(x + 0.044715f*x*x*x));
  return 0.5f*x*(1.f+t);
}
__device__ __forceinline__ float gelu_bwd_f(float x){
  float t = tanh_f(0.79788456f*(x + 0.044715f*x*x*x));
  return 0.5f*x*(1.f-t*t)*(0.79788456f + 0.1070322243f*x*x) + 0.5f*(1.f+t);
}
__device__ __forceinline__ v8s ld8(const unsigned short* p){
  v4s lo = *(const v4s*)p, hi = *(const v4s*)(p+4);
  v8s r;
  r[0]=lo[0];r[1]=lo[1];r[2]=lo[2];r[3]=lo[3];
  r[4]=hi[0];r[5]=hi[1];r[6]=hi[2];r[7]=hi[3];
  return r;
}

// ---------------- f32 -> bf16 weight conversion, 4 matrices per launch ----------------
__global__ __launch_bounds__(256) void wcvt_kernel(
    const float* __restrict__ s0, const float* __restrict__ s1,
    const float* __restrict__ s2, const float* __restrict__ s3,
    unsigned short* __restrict__ d0, unsigned short* __restrict__ d1,
    unsigned short* __restrict__ d2, unsigned short* __restrict__ d3)
{
  int y = blockIdx.y;
  const float* s = y==0?s0:(y==1?s1:(y==2?s2:s3));
  unsigned short* d = y==0?d0:(y==1?d1:(y==2?d2:d3));
  int tid = blockIdx.x*256 + threadIdx.x;   // 16384 threads
  #pragma unroll 4
  for (int i=0;i<16;i++){
    size_t o = (size_t)i*65536 + (size_t)tid*4;
    float4 v = *(const float4*)&s[o];
    v4s p;
    p[0]=(short)fbf(v.x); p[1]=(short)fbf(v.y); p[2]=(short)fbf(v.z); p[3]=(short)fbf(v.w);
    *(v4s*)&d[o] = p;
  }
}

// ---------------- LayerNorm over D=1024, one block per row; optional f32/bf16 outs ----------------
__global__ __launch_bounds__(256) void ln_kernel(
    const float* __restrict__ X, const float* __restrict__ g,
    const float* __restrict__ bta, float* __restrict__ out,
    unsigned short* __restrict__ outbf)
{
  __shared__ float red[4];
  int row = blockIdx.x, t = threadIdx.x;
  const float* xr = X + (size_t)row*1024;
  float v[4];
  #pragma unroll
  for (int i=0;i<4;i++) v[i] = xr[t + i*256];
  float s = v[0]+v[1]+v[2]+v[3];
  s = wsum(s);
  if ((t&63)==0) red[t>>6]=s;
  __syncthreads();
  float mu = (red[0]+red[1]+red[2]+red[3])*(1.f/1024.f);
  float q=0.f;
  #pragma unroll
  for (int i=0;i<4;i++){ float dd=v[i]-mu; q+=dd*dd; }
  q = wsum(q);
  __syncthreads();
  if ((t&63)==0) red[t>>6]=q;
  __syncthreads();
  float var = (red[0]+red[1]+red[2]+red[3])*(1.f/1024.f);
  float rs = rsqrtf(var+1e-6f);
  #pragma unroll
  for (int i=0;i<4;i++){
    int c = t+i*256;
    float vv = (v[i]-mu)*rs*g[c] + bta[c];
    if (out)   out[(size_t)row*1024+c] = vv;
    if (outbf) outbf[(size_t)row*1024+c] = fbf(vv);
  }
}

// ---- MFMA GEMM (bf16 A, bf16 pre-converted weights), optionally 3-way fused along N.
// Round-12: staging via global_load_lds(16B) into linear [128][64] LDS with XOR swizzle:
// write side: source chunk = chunk ^ (row&7) (linear LDS dest); read side: byte ^= (row&7)<<4.
// Reads are 2-way bank-aliased (free); staging register round-trip eliminated.
__global__ __launch_bounds__(256, 2) void gemm_kernel(
    const unsigned short* __restrict__ A_bf,
    const unsigned short* __restrict__ B0, const unsigned short* __restrict__ B1, const unsigned short* __restrict__ B2,
    const float* __restrict__ bias0, const float* __restrict__ bias1, const float* __restrict__ bias2,
    const float* __restrict__ res, const float* __restrict__ gate,
    float* __restrict__ out0, float* __restrict__ out1, float* __restrict__ out2,
    unsigned short* __restrict__ obf0, unsigned short* __restrict__ obf1, unsigned short* __restrict__ obf2)
{
  __shared__ __attribute__((aligned(16))) unsigned short a_lds[128*64];
  __shared__ __attribute__((aligned(16))) unsigned short b_lds[128*64];
  int t=threadIdx.x, w=t>>6, lane=t&63;
  int widx = blockIdx.x>>3;
  const unsigned short* Bw = widx==0?B0:(widx==1?B1:B2);
  const float* bias = widx==0?bias0:(widx==1?bias1:bias2);
  float* out        = widx==0?out0:(widx==1?out1:out2);
  unsigned short* obf = widx==0?obf0:(widx==1?obf1:obf2);
  int gm = blockIdx.y*128, gn = (blockIdx.x&7)*128;
  int wm=(w>>1)*64, wn=(w&1)*64, lr=lane&15;
  int rl = lane>>3, j0 = lane&7;          // staging: row-in-chunk, 16B-chunk index
  int qb = (lane>>4)*16;                  // read: byte offset of k-quad within 64B half
  v4f acc[4][4];
  #pragma unroll
  for (int i=0;i<4;i++)
    #pragma unroll
    for (int j=0;j<4;j++){ v4f z={0.f,0.f,0.f,0.f}; acc[i][j]=z; }
  for (int kk=0; kk<1024; kk+=64){
    __syncthreads();
    #pragma unroll
    for (int c=0;c<4;c++){
      int r = w*32 + c*8 + rl;                       // LDS row 0..127
      int js = (j0 ^ (r&7))*16;                      // swizzled source byte-in-row
      const char* ga = (const char*)A_bf + ((size_t)(gm+r)*1024 + kk)*2 + js;
      const char* gb = (const char*)Bw  + ((size_t)(gn+r)*1024 + kk)*2 + js;
      __builtin_amdgcn_global_load_lds(
          (const __attribute__((address_space(1))) void*)ga,
          (__attribute__((address_space(3))) void*)&a_lds[(w*32+c*8)*64], 16, 0, 0);
      __builtin_amdgcn_global_load_lds(
          (const __attribute__((address_space(1))) void*)gb,
          (__attribute__((address_space(3))) void*)&b_lds[(w*32+c*8)*64], 16, 0, 0);
    }
    __syncthreads();
    #pragma unroll
    for (int k2=0;k2<2;k2++){
      v8s af[4], bfr[4];
      #pragma unroll
      for (int i=0;i<4;i++){
        int R = wm+i*16+lr;
        int byt = (k2*64 + qb) ^ ((R&7)<<4);
        af[i] = ld8((const unsigned short*)((const char*)&a_lds[R*64] + byt));
      }
      #pragma unroll
      for (int j=0;j<4;j++){
        int R = wn+j*16+lr;
        int byt = (k2*64 + qb) ^ ((R&7)<<4);
        bfr[j] = ld8((const unsigned short*)((const char*)&b_lds[R*64] + byt));
      }
      #pragma unroll
      for (int i=0;i<4;i++)
        #pragma unroll
        for (int j=0;j<4;j++)
          acc[i][j] = __builtin_amdgcn_mfma_f32_16x16x32_bf16(af[i], bfr[j], acc[i][j], 0,0,0);
    }
  }
  int quad = lane>>4;
  #pragma unroll
  for (int j=0;j<4;j++){
    int gc = gn + wn + j*16 + lr;
    float bval = bias ? bias[gc] : 0.f;
    float gval = gate ? tanh_f(gate[gc]) : 1.f;
    #pragma unroll
    for (int i=0;i<4;i++){
      #pragma unroll
      for (int r=0;r<4;r++){
        int grow = gm + wm + i*16 + quad*4 + r;
        float v = (acc[i][j][r] + bval)*gval;
        if (res) v += res[(size_t)grow*1024 + gc];
        size_t oi = (size_t)grow*1024 + gc;
        if (out) out[oi] = v;
        if (obf) obf[oi] = fbf(v);
      }
    }
  }
}

// ---------------- MFMA flash attention (bf16 in), block = (b,h,q-tile of 64) ----------------
__global__ __launch_bounds__(256) void attn_kernel(
    const unsigned short* __restrict__ Q, const unsigned short* __restrict__ K,
    const unsigned short* __restrict__ V, float* __restrict__ O,
    unsigned short* __restrict__ Obf)
{
  __shared__ __attribute__((aligned(16))) unsigned short q_l[64*68];
  __shared__ __attribute__((aligned(16))) unsigned short k_l[64*68];
  __shared__ __attribute__((aligned(16))) unsigned short vt_l[64*68]; // V^T [d][j]
  __shared__ __attribute__((aligned(16))) unsigned short p_l[64*68];
  int t=threadIdx.x, w=t>>6, lane=t&63, q=lane>>4, l16=lane&15;
  int qt = blockIdx.x & 15, bh = blockIdx.x >> 4;
  int b = bh >> 4, h = bh & 15;
  const size_t base = ((size_t)b*1024)*1024 + (size_t)h*64;
  #pragma unroll
  for (int pass=0;pass<4;pass++){
    int slot=t+pass*256, row=slot>>4, c4=(slot&15)*4;
    v4s qv = *(const v4s*)&Q[base + (size_t)(qt*64+row)*1024 + c4];
    *(v4s*)&q_l[row*68+c4]=qv;
  }
  float mi[4], li[4];
  v4f o[4];
  #pragma unroll
  for (int r=0;r<4;r++){ mi[r]=-1e30f; li[r]=0.f; }
  #pragma unroll
  for (int dtn=0;dtn<4;dtn++){ v4f z={0.f,0.f,0.f,0.f}; o[dtn]=z; }
  for (int kt=0; kt<=qt; kt++){
    __syncthreads();
    #pragma unroll
    for (int pass=0;pass<4;pass++){
      int slot=t+pass*256, row=slot>>4, c4=(slot&15)*4;
      v4s kv = *(const v4s*)&K[base + (size_t)(kt*64+row)*1024 + c4];
      *(v4s*)&k_l[row*68+c4]=kv;
      v4s vv = *(const v4s*)&V[base + (size_t)(kt*64+row)*1024 + c4];
      vt_l[(c4+0)*68+row]=(unsigned short)vv[0];
      vt_l[(c4+1)*68+row]=(unsigned short)vv[1];
      vt_l[(c4+2)*68+row]=(unsigned short)vv[2];
      vt_l[(c4+3)*68+row]=(unsigned short)vv[3];
    }
    __syncthreads();
    // S = Q@K^T (wave rows w*16..+15)
    v4f s[4];
    #pragma unroll
    for (int nt=0;nt<4;nt++){ v4f z={0.f,0.f,0.f,0.f}; s[nt]=z; }
    #pragma unroll
    for (int k2=0;k2<2;k2++){
      v8s af = ld8(&q_l[(w*16+l16)*68 + k2*32+q*8]);
      #pragma unroll
      for (int nt=0;nt<4;nt++){
        v8s bf = ld8(&k_l[(nt*16+l16)*68 + k2*32+q*8]);
        s[nt] = __builtin_amdgcn_mfma_f32_16x16x32_bf16(af, bf, s[nt], 0,0,0);
      }
    }
    bool diag = (kt==qt);
    #pragma unroll
    for (int r=0;r<4;r++){
      int row_l = w*16+q*4+r;
      float mx=-1e30f;
      #pragma unroll
      for (int nt=0;nt<4;nt++){
        int col=nt*16+l16;
        float sv = s[nt][r]*0.125f;
        if (diag && col>row_l) sv=-1e30f;
        s[nt][r]=sv; mx=fmaxf(mx,sv);
      }
      #pragma unroll
      for (int off=1;off<16;off<<=1) mx=fmaxf(mx,__shfl_xor(mx,off,16));
      float mnew=fmaxf(mi[r],mx);
      float aexp=__expf(mi[r]-mnew);
      float ps=0.f;
      #pragma unroll
      for (int nt=0;nt<4;nt++){
        float p=__expf(s[nt][r]-mnew);
        s[nt][r]=p; ps+=p;
      }
      #pragma unroll
      for (int off=1;off<16;off<<=1) ps+=__shfl_xor(ps,off,16);
      li[r]=li[r]*aexp+ps; mi[r]=mnew;
      #pragma unroll
      for (int dtn=0;dtn<4;dtn++) o[dtn][r]*=aexp;
      #pragma unroll
      for (int nt=0;nt<4;nt++) p_l[row_l*68 + nt*16+l16]=fbf(s[nt][r]);
    }
    __syncthreads();
    // O += P@V
    #pragma unroll
    for (int k2=0;k2<2;k2++){
      v8s af = ld8(&p_l[(w*16+l16)*68 + k2*32+q*8]);
      #pragma unroll
      for (int dtn=0;dtn<4;dtn++){
        v8s bf = ld8(&vt_l[(dtn*16+l16)*68 + k2*32+q*8]);
        o[dtn] = __builtin_amdgcn_mfma_f32_16x16x32_bf16(af, bf, o[dtn], 0,0,0);
      }
    }
  }
  #pragma unroll
  for (int dtn=0;dtn<4;dtn++)
    #pragma unroll
    for (int r=0;r<4;r++){
      float vv = o[dtn][r]/li[r];
      size_t oi = base + (size_t)(qt*64+w*16+q*4+r)*1024 + dtn*16+l16;
      if (O)   O[oi] = vv;
      if (Obf) Obf[oi] = fbf(vv);
    }
}

// ------- XQ/XK normalize + target fuse; write TTT layouts. wave = (b,s,h) -------
__global__ __launch_bounds__(256) void xqkv_kernel(
    const float* __restrict__ XQ, const float* __restrict__ XK,
    const float* __restrict__ XV, const float* __restrict__ nw,
    const float* __restrict__ nb, const float* __restrict__ eta,
    float* __restrict__ xqt, float* __restrict__ tgtp,
    unsigned short* __restrict__ xq_bf, unsigned short* __restrict__ xk_bf,
    unsigned short* __restrict__ xkTe_bf)
{
  int gw = (int)((blockIdx.x*256 + threadIdx.x)>>6);
  int lane = threadIdx.x & 63;
  int h = gw & 15, s = (gw>>4)&1023, b = gw>>14;
  size_t src = ((size_t)(b*1024+s))*1024 + h*64 + lane;
  float xq = XQ[src], xk = XK[src], xv = XV[src];
  float nq = sqrtf(wsum(xq*xq));
  float nk = sqrtf(wsum(xk*xk));
  float xqn = xq / fmaxf(nq, 1e-12f);
  float xkn = xk / fmaxf(nk, 1e-12f);
  float mu = wsum(xv)*(1.f/64.f);
  float xm = xv-mu;
  float var = wsum(xm*xm)*(1.f/64.f);
  float xvh = xm*rsqrtf(var+1e-6f);
  float tg = nw[h*64+lane]*xvh + nb[h*64+lane];   // xvn - xkn exactly
  float et = eta[((size_t)(b*16+h))*1024 + s];
  size_t dst = ((size_t)(b*16+h)*1024 + s)*64 + lane;
  xq_bf[dst]=fbf(xqn); xk_bf[dst]=fbf(xkn);
  xkTe_bf[((size_t)(b*16+h)*64 + lane)*1024 + s] = fbf(-et*xkn);
  int n_ = s>>6, row = s&63;
  int wv = row>>4, qq = (row>>2)&3, rr = row&3;
  int nt_ = lane>>4, l16_ = lane&15;
  int tt = wv*64 + qq*16 + l16_;
  size_t dst2 = (size_t)(b*16+h)*65536 + (size_t)n_*4096 + (size_t)tt*16 + nt_*4 + rr;
  xqt[dst2]=xqn; tgtp[dst2]=tg;
}

// ------- eta[b,h,s] = sigmoid(x[b,s,:]·lr_w[h,:] + lr_b[h]) / 64. wave = (b,s) -------
__global__ __launch_bounds__(256) void eta_kernel(
    const float* __restrict__ Xb, const float* __restrict__ lrw,
    const float* __restrict__ lrb, float* __restrict__ eta)
{
  int gw = (int)((blockIdx.x*256 + threadIdx.x)>>6);
  int lane = threadIdx.x & 63;
  int s = gw & 1023, b = gw >> 10;
  const float* xrow = Xb + ((size_t)(b*1024+s))*1024;
  float xr[16];
  #pragma unroll
  for (int i=0;i<16;i++) xr[i] = xrow[i*64+lane];
  #pragma unroll 1
  for (int h=0;h<16;h++){
    const float* wr = lrw + h*1024;
    float acc=0.f;
    #pragma unroll
    for (int i=0;i<16;i++) acc += xr[i]*wr[i*64+lane];
    acc = wsum(acc);
    if (lane==h){
      float vv = acc + lrb[h];
      float sg = 1.f/(1.f+__expf(-vv));
      eta[((size_t)(b*16+h))*1024 + s] = sg*(1.f/64.f);
    }
  }
}

// ---------------- TTT scan (MFMA, LDS-resident), 512 threads = 8 waves ----------------
// Frozen at round-8's measured-best form (489-491us): register-diet gbp/x2bp,
// two-barrier LN2, per-phase loads, ln_scr stride 8.
__global__ __launch_bounds__(512, 2) __attribute__((amdgpu_waves_per_eu(2, 2)))
void scan_kernel(
    const float* __restrict__ xqt, const float* __restrict__ tgtp,
    const unsigned short* __restrict__ xq_bf, const unsigned short* __restrict__ xk_bf,
    const unsigned short* __restrict__ xkTe_bf, const float* __restrict__ eta,
    const float* __restrict__ W1in, const float* __restrict__ b1in,
    const float* __restrict__ W2in, const float* __restrict__ b2in,
    const float* __restrict__ nw, const float* __restrict__ nb,
    float* __restrict__ tout)
{
  __shared__ __attribute__((aligned(16))) unsigned short W1t[256*68];  // W1^T [n][k]
  __shared__ __attribute__((aligned(16))) unsigned short W2T[64*260];  // W2^T [d][k]
  __shared__ __attribute__((aligned(16))) unsigned short X2s[64*260];  // X2 [m][n]
  __shared__ __attribute__((aligned(16))) unsigned short GXu[256*68];  // GZ1t [n][j] / X2b [m][n](260)
  __shared__ __attribute__((aligned(16))) unsigned short GZ2t[64*68];  // gZ2^T [d][j]
  __shared__ __attribute__((aligned(16))) unsigned short AMs[64*68];   // -tril(eta*(A+1)) [m][j]
  __shared__ float ln_scr[64*8];
  __shared__ float eta_s[64], b1_s[256], b2_s[64], nw_s[64], nb_s[64];

  const int t=threadIdx.x, w=t>>6, lane=t&63, q=lane>>4, l16=lane&15;
  const int bh=blockIdx.x, b=bh>>4, h=bh&15;
  const int mt=w>>1, half=w&1, nh=half*8, nh4=half*2;
  const float* xq_g  = xqt  + (size_t)bh*65536;
  const float* tgt_g = tgtp + (size_t)bh*65536;
  const unsigned short* xqb_g = xq_bf  + (size_t)bh*65536;
  const unsigned short* xkb_g = xk_bf  + (size_t)bh*65536;
  const unsigned short* xkT_g = xkTe_bf + (size_t)bh*65536;
  const float* eta_g = eta + (size_t)bh*1024;

  // W1 masters (C-frag): rows mt*16+q*4+r, cols (nh+nt)*16+l16
  v4f w1r[8];
  #pragma unroll
  for (int nt=0;nt<8;nt++){
    int col=(nh+nt)*16+l16;
    #pragma unroll
    for (int r=0;r<4;r++) w1r[nt][r] = W1in[h*16384 + (mt*16+q*4+r)*256 + col];
  }
  // W2 masters: rows (w*2+mi)*16+q*4+r, cols nt*16+l16
  v4f w2r[2][4];
  #pragma unroll
  for (int mi=0;mi<2;mi++)
    #pragma unroll
    for (int nt=0;nt<4;nt++){
      int col=nt*16+l16;
      #pragma unroll
      for (int r=0;r<4;r++) w2r[mi][nt][r] = W2in[h*16384 + ((w*2+mi)*16+q*4+r)*64 + col];
    }
  if (t<256) b1_s[t]=b1in[h*256+t];
  if (t<64){ b2_s[t]=b2in[h*64+t]; nw_s[t]=nw[h*64+t]; nb_s[t]=nb[h*64+t]; }

  float bacc=0.f, bacc2=0.f;   // deferred bias updates

  for (int n=0;n<16;n++){
    // prefetch this step's A-fragments (global, safe pre-barrier)
    v8s xkf[2], xqf[2];
    #pragma unroll
    for (int kt=0;kt<2;kt++){
      xkf[kt] = ld8(&xkb_g[(size_t)n*4096 + (mt*16+l16)*64 + kt*32+q*8]);
      xqf[kt] = ld8(&xqb_g[(size_t)n*4096 + (mt*16+l16)*64 + kt*32+q*8]);
    }
    __syncthreads();                                        // B1: prev-step readers done
    if (t<256) b1_s[t] -= bacc;
    if (t<64){ b2_s[t] -= bacc2; eta_s[t]=eta_g[n*64+t]; }
    // ---- stage bf16 W copies (transposed) ----
    #pragma unroll
    for (int nt=0;nt<8;nt++){
      int col=(nh+nt)*16+l16;
      #pragma unroll
      for (int pr=0;pr<2;pr++){
        unsigned lo=fbf(w1r[nt][pr*2]), hi=fbf(w1r[nt][pr*2+1]);
        *(unsigned*)&W1t[col*68 + mt*16+q*4 + pr*2] = lo | (hi<<16);
      }
    }
    #pragma unroll
    for (int mi=0;mi<2;mi++)
      #pragma unroll
      for (int nt=0;nt<4;nt++){
        int col=nt*16+l16;
        #pragma unroll
        for (int pr=0;pr<2;pr++){
          unsigned lo=fbf(w2r[mi][nt][pr*2]), hi=fbf(w2r[mi][nt][pr*2+1]);
          *(unsigned*)&W2T[col*260 + (w*2+mi)*16+q*4 + pr*2] = lo | (hi<<16);
        }
      }
    __syncthreads();                                        // B2: staging visible

    // ---- P1: Z1 = xk@W1 + b1; X2 -> X2s; gelu' packed bf16 -> gbp. A4 -> AMs. ----
    unsigned gbp[16];
    {
      v4f a1[8];
      #pragma unroll
      for (int i=0;i<8;i++){ v4f z={0.f,0.f,0.f,0.f}; a1[i]=z; }
      #pragma unroll
      for (int kt=0;kt<2;kt++){
        #pragma unroll
        for (int nt=0;nt<8;nt++){
          v8s bf = ld8(&W1t[((nh+nt)*16+l16)*68 + kt*32+q*8]);
          a1[nt] = __builtin_amdgcn_mfma_f32_16x16x32_bf16(xkf[kt], bf, a1[nt], 0,0,0);
        }
      }
      #pragma unroll
      for (int nt=0;nt<8;nt++){
        int col=(nh+nt)*16+l16; float bb=b1_s[col];
        float zz[4];
        #pragma unroll
        for (int r=0;r<4;r++){
          float z=clampv(a1[nt][r]+bb); zz[r]=z;
          X2s[(mt*16+q*4+r)*260+col]=fbf(clampv(gelu_f(z)));
        }
        #pragma unroll
        for (int pr=0;pr<2;pr++)
          gbp[nt*2+pr] = (unsigned)fbf(gelu_bwd_f(zz[pr*2+0]))
                       | ((unsigned)fbf(gelu_bwd_f(zz[pr*2+1]))<<16);
      }
    }
    {
      v4f a4[2];
      #pragma unroll
      for (int i=0;i<2;i++){ v4f z={0.f,0.f,0.f,0.f}; a4[i]=z; }
      #pragma unroll
      for (int kt=0;kt<2;kt++){
        #pragma unroll
        for (int nt=0;nt<2;nt++){
          v8s bf = ld8(&xkb_g[(size_t)n*4096 + ((nh4+nt)*16+l16)*64 + kt*32+q*8]);
          a4[nt] = __builtin_amdgcn_mfma_f32_16x16x32_bf16(xqf[kt], bf, a4[nt], 0,0,0);
        }
      }
      #pragma unroll
      for (int nt=0;nt<2;nt++){
        int col=(nh4+nt)*16+l16;
        float ec=eta_s[col];
        #pragma unroll
        for (int r=0;r<4;r++){
          int row=mt*16+q*4+r;
          AMs[row*68+col] = (col<=row) ? fbf(-ec*(a4[nt][r]+1.f)) : (unsigned short)0;
        }
      }
    }

    // ---- P2: Z2 = X2@W2 + b2 ; LN2 (cross-half via ln_scr) -> GZ2t ----
    {
      const float* tc = tgt_g + (size_t)n*4096 + (size_t)(mt*64+q*16+l16)*16 + nh4*4;
      float4 ta=*(const float4*)tc, tb=*(const float4*)(tc+4);
      float tgs[8]={ta.x,ta.y,ta.z,ta.w,tb.x,tb.y,tb.z,tb.w};
      v4f a2[2];
      #pragma unroll
      for (int i=0;i<2;i++){ v4f z={0.f,0.f,0.f,0.f}; a2[i]=z; }
      #pragma unroll
      for (int kt=0;kt<8;kt++){
        v8s af = ld8(&X2s[(mt*16+l16)*260 + kt*32+q*8]);
        #pragma unroll
        for (int nt=0;nt<2;nt++){
          v8s bf = ld8(&W2T[((nh4+nt)*16+l16)*260 + kt*32+q*8]);
          a2[nt] = __builtin_amdgcn_mfma_f32_16x16x32_bf16(af, bf, a2[nt], 0,0,0);
        }
      }
      float z2[2][4];
      #pragma unroll
      for (int nt=0;nt<2;nt++){
        float bb=b2_s[(nh4+nt)*16+l16];
        #pragma unroll
        for (int r=0;r<4;r++) z2[nt][r]=clampv(a2[nt][r]+bb);
      }
      #pragma unroll
      for (int r=0;r<4;r++){
        float s1v=z2[0][r]+z2[1][r];
        float s2v=z2[0][r]*z2[0][r]+z2[1][r]*z2[1][r];
        #pragma unroll
        for (int off=1;off<16;off<<=1){ s1v+=__shfl_xor(s1v,off,16); s2v+=__shfl_xor(s2v,off,16); }
        if (l16==0){ int row=mt*16+q*4+r; ln_scr[row*8+half]=s1v; ln_scr[row*8+2+half]=s2v; }
      }
      __syncthreads();                                      // B3
      float muv[4], istd[4];
      #pragma unroll
      for (int r=0;r<4;r++){
        int row=mt*16+q*4+r;
        float S1=ln_scr[row*8+0]+ln_scr[row*8+1];
        float S2=ln_scr[row*8+2]+ln_scr[row*8+3];
        float mu=S1*(1.f/64.f);
        float var=fmaxf(S2*(1.f/64.f)-mu*mu, 0.f);
        muv[r]=mu; istd[r]=rsqrtf(var+1e-6f);
      }
      float xh[2][4], gh[2][4];
      #pragma unroll
      for (int nt=0;nt<2;nt++){
        int col=(nh4+nt)*16+l16;
        float gw_=nw_s[col], gb_=nb_s[col];
        #pragma unroll
        for (int r=0;r<4;r++){
          float x_=(z2[nt][r]-muv[r])*istd[r];
          float tgv = tgs[nt*4+r];
          xh[nt][r]=x_;
          gh[nt][r]=(gw_*x_+gb_-tgv)*gw_;
        }
      }
      #pragma unroll
      for (int r=0;r<4;r++){
        float t1=gh[0][r]+gh[1][r];
        float t2=gh[0][r]*xh[0][r]+gh[1][r]*xh[1][r];
        #pragma unroll
        for (int off=1;off<16;off<<=1){ t1+=__shfl_xor(t1,off,16); t2+=__shfl_xor(t2,off,16); }
        if (l16==0){ int row=mt*16+q*4+r; ln_scr[row*8+4+half]=t1; ln_scr[row*8+6+half]=t2; }
      }
      __syncthreads();                                      // B4
      #pragma unroll
      for (int nt=0;nt<2;nt++){
        int col=(nh4+nt)*16+l16;
        #pragma unroll
        for (int pr=0;pr<2;pr++){
          unsigned pk[2];
          #pragma unroll
          for (int k2=0;k2<2;k2++){
            int r=pr*2+k2;
            int row=mt*16+q*4+r;
            float G1s=ln_scr[row*8+4]+ln_scr[row*8+5];
            float G2s=ln_scr[row*8+6]+ln_scr[row*8+7];
            float gz=(64.f*gh[nt][r]-G1s-xh[nt][r]*G2s)*istd[r]*(1.f/64.f);
            pk[k2]=fbf(clampv(gz));
          }
          *(unsigned*)&GZ2t[col*68 + mt*16+q*4 + pr*2] = pk[0] | (pk[1]<<16);
        }
      }
    }
    __syncthreads();                                        // B5: GZ2t (both halves) visible

    // ---- P3: gZ1 = (gZ2@W2^T) * gelu'(Z1) -> GZ1t [n][j] ----
    {
      v4f a3[8];
      #pragma unroll
      for (int i=0;i<8;i++){ v4f z={0.f,0.f,0.f,0.f}; a3[i]=z; }
      #pragma unroll
      for (int kt=0;kt<2;kt++){
        v8s af;
        #pragma unroll
        for (int j=0;j<8;j++) af[j]=(short)GZ2t[(kt*32+q*8+j)*68 + mt*16+l16];
        #pragma unroll
        for (int nt=0;nt<8;nt++){
          int nb0=(nh+nt)*16+l16;
          v8s bf;
          #pragma unroll
          for (int j=0;j<8;j++) bf[j]=(short)W2T[(kt*32+q*8+j)*260 + nb0];
          a3[nt] = __builtin_amdgcn_mfma_f32_16x16x32_bf16(af, bf, a3[nt], 0,0,0);
        }
      }
      #pragma unroll
      for (int nt=0;nt<8;nt++){
        int col=(nh+nt)*16+l16;
        #pragma unroll
        for (int pr=0;pr<2;pr++){
          float d0=bfu((unsigned short)(gbp[nt*2+pr]&0xffffu));
          float d1=bfu((unsigned short)(gbp[nt*2+pr]>>16));
          float g0=clampv(a3[nt][pr*2+0]*d0);
          float g1=clampv(a3[nt][pr*2+1]*d1);
          unsigned lo=fbf(g0), hi=fbf(g1);
          *(unsigned*)&GXu[col*68 + mt*16+q*4 + pr*2] = lo | (hi<<16);
        }
      }
    }
    __syncthreads();                                        // B6: GZ1t visible

    // ---- P5: Z1b = xq@W1 + AMs@gZ1 + b1 ; H1 in-place: W1 += (-eta xk)^T @ gZ1 ;
    //      then compress X2b = fbf(gelu(Z1b+b1)) into x2bp BEFORE the barrier. ----
    unsigned x2bp[16];
    {
      float p0=0.f,p1=0.f,p2=0.f,p3=0.f;
      if (t<256){
        #pragma unroll
        for (int j4=0;j4<16;j4++){
          v4s v=*(const v4s*)&GXu[t*68+j4*4];
          p0 += eta_s[j4*4+0]*bfu((unsigned short)v[0]);
          p1 += eta_s[j4*4+1]*bfu((unsigned short)v[1]);
          p2 += eta_s[j4*4+2]*bfu((unsigned short)v[2]);
          p3 += eta_s[j4*4+3]*bfu((unsigned short)v[3]);
        }
      }
      bacc=(p0+p1)+(p2+p3);
      v8s xef[2];
      #pragma unroll
      for (int kt=0;kt<2;kt++)
        xef[kt] = ld8(&xkT_g[(size_t)(mt*16+l16)*1024 + n*64 + kt*32+q*8]);
      v4f a5[8];
      #pragma unroll
      for (int i=0;i<8;i++){ v4f z={0.f,0.f,0.f,0.f}; a5[i]=z; }
      #pragma unroll
      for (int kt=0;kt<2;kt++){
        #pragma unroll
        for (int nt=0;nt<8;nt++){
          v8s bf = ld8(&W1t[((nh+nt)*16+l16)*68 + kt*32+q*8]);
          a5[nt] = __builtin_amdgcn_mfma_f32_16x16x32_bf16(xqf[kt], bf, a5[nt], 0,0,0);
        }
      }
      #pragma unroll
      for (int kt=0;kt<2;kt++){
        v8s afA = ld8(&AMs[(mt*16+l16)*68 + kt*32+q*8]);
        #pragma unroll
        for (int nt=0;nt<8;nt++){
          v8s bf = ld8(&GXu[((nh+nt)*16+l16)*68 + kt*32+q*8]);
          a5[nt] = __builtin_amdgcn_mfma_f32_16x16x32_bf16(afA, bf, a5[nt], 0,0,0);
          w1r[nt] = __builtin_amdgcn_mfma_f32_16x16x32_bf16(xef[kt], bf, w1r[nt], 0,0,0);
        }
      }
      #pragma unroll
      for (int nt=0;nt<8;nt++){
        float bb=b1_s[(nh+nt)*16+l16];
        #pragma unroll
        for (int pr=0;pr<2;pr++){
          float z0=clampv(a5[nt][pr*2+0]+bb);
          float z1=clampv(a5[nt][pr*2+1]+bb);
          x2bp[nt*2+pr] = (unsigned)fbf(clampv(gelu_f(z0)))
                        | ((unsigned)fbf(clampv(gelu_f(z1)))<<16);
        }
      }
    }
    __syncthreads();                                        // B7: GXu/AMs reads done

    // ---- X2b (packed) -> GXu row-major [m][n](260) ----
    #pragma unroll
    for (int nt=0;nt<8;nt++){
      int col=(nh+nt)*16+l16;
      #pragma unroll
      for (int pr=0;pr<2;pr++){
        int row0=mt*16+q*4+pr*2;
        GXu[row0*260+col]     = (unsigned short)(x2bp[nt*2+pr]&0xffffu);
        GXu[(row0+1)*260+col] = (unsigned short)(x2bp[nt*2+pr]>>16);
      }
    }
    __syncthreads();                                        // B8: X2b visible

    // ---- P6: AMs = -tril(eta_j*(X2b@X2^T + 1)) ; b2 colsum (deferred) ----
    {
      float p0=0.f,p1=0.f,p2=0.f,p3=0.f;
      if (t<64){
        #pragma unroll
        for (int j4=0;j4<16;j4++){
          v4s v=*(const v4s*)&GZ2t[t*68+j4*4];
          p0 += eta_s[j4*4+0]*bfu((unsigned short)v[0]);
          p1 += eta_s[j4*4+1]*bfu((unsigned short)v[1]);
          p2 += eta_s[j4*4+2]*bfu((unsigned short)v[2]);
          p3 += eta_s[j4*4+3]*bfu((unsigned short)v[3]);
        }
      }
      bacc2=(p0+p1)+(p2+p3);
      v4f a7[2];
      #pragma unroll
      for (int i=0;i<2;i++){ v4f z={0.f,0.f,0.f,0.f}; a7[i]=z; }
      #pragma unroll
      for (int kt=0;kt<8;kt++){
        v8s af = ld8(&GXu[(mt*16+l16)*260 + kt*32+q*8]);   // X2b
        #pragma unroll
        for (int nt=0;nt<2;nt++){
          v8s bf = ld8(&X2s[((nh4+nt)*16+l16)*260 + kt*32+q*8]);
          a7[nt] = __builtin_amdgcn_mfma_f32_16x16x32_bf16(af, bf, a7[nt], 0,0,0);
        }
      }
      #pragma unroll
      for (int nt=0;nt<2;nt++){
        int col=(nh4+nt)*16+l16;
        float ec=eta_s[col];
        #pragma unroll
        for (int r=0;r<4;r++){
          int row=mt*16+q*4+r;
          AMs[row*68+col] = (col<=row) ? fbf(-ec*(a7[nt][r]+1.f)) : (unsigned short)0;
        }
      }
    }
    __syncthreads();                                        // B9: AMs visible

    // ---- P7: Z2b = X2b@W2 + AMs@gZ2 + b2 ; LN7 -> tout ; H2 in-place ----
    {
      const float* xc = xq_g + (size_t)n*4096 + (size_t)(mt*64+q*16+l16)*16 + nh4*4;
      float4 xa=*(const float4*)xc, xb=*(const float4*)(xc+4);
      float xqs[8]={xa.x,xa.y,xa.z,xa.w,xb.x,xb.y,xb.z,xb.w};
      v4f a8[2];
      #pragma unroll
      for (int i=0;i<2;i++){ v4f z={0.f,0.f,0.f,0.f}; a8[i]=z; }
      float b2old[2];
      #pragma unroll
      for (int nt=0;nt<2;nt++) b2old[nt]=b2_s[(nh4+nt)*16+l16];
      #pragma unroll
      for (int kt=0;kt<8;kt++){
        v8s af = ld8(&GXu[(mt*16+l16)*260 + kt*32+q*8]);   // X2b
        #pragma unroll
        for (int nt=0;nt<2;nt++){
          v8s bf = ld8(&W2T[((nh4+nt)*16+l16)*260 + kt*32+q*8]);
          a8[nt] = __builtin_amdgcn_mfma_f32_16x16x32_bf16(af, bf, a8[nt], 0,0,0);
        }
      }
      #pragma unroll
      for (int kt=0;kt<2;kt++){
        v8s afm = ld8(&AMs[(mt*16+l16)*68 + kt*32+q*8]);
        #pragma unroll
        for (int nt=0;nt<2;nt++){
          v8s bf = ld8(&GZ2t[((nh4+nt)*16+l16)*68 + kt*32+q*8]);
          a8[nt] = __builtin_amdgcn_mfma_f32_16x16x32_bf16(afm, bf, a8[nt], 0,0,0);
        }
      }
      float z2b[2][4];
      #pragma unroll
      for (int nt=0;nt<2;nt++)
        #pragma unroll
        for (int r=0;r<4;r++) z2b[nt][r]=clampv(a8[nt][r]+b2old[nt]);
      #pragma unroll
      for (int r=0;r<4;r++){
        float s1v=z2b[0][r]+z2b[1][r];
        float s2v=z2b[0][r]*z2b[0][r]+z2b[1][r]*z2b[1][r];
        #pragma unroll
        for (int off=1;off<16;off<<=1){ s1v+=__shfl_xor(s1v,off,16); s2v+=__shfl_xor(s2v,off,16); }
        if (l16==0){ int row=mt*16+q*4+r; ln_scr[row*8+half]=s1v; ln_scr[row*8+2+half]=s2v; }
      }
      __syncthreads();                                      // B10
      #pragma unroll
      for (int r=0;r<4;r++){
        int row=mt*16+q*4+r;
        float S1=ln_scr[row*8+0]+ln_scr[row*8+1];
        float S2=ln_scr[row*8+2]+ln_scr[row*8+3];
        float mu=S1*(1.f/64.f);
        float var=fmaxf(S2*(1.f/64.f)-mu*mu, 0.f);
        float istd=rsqrtf(var+1e-6f);
        #pragma unroll
        for (int nt=0;nt<2;nt++){
          int col=(nh4+nt)*16+l16;
          float x_=(z2b[nt][r]-mu)*istd;
          float outv = xqs[nt*4+r] + x_*nw_s[col] + nb_s[col];
          tout[((size_t)(b*1024 + n*64 + row))*1024 + h*64 + col] = outv;
        }
      }
      // H2 in-place: W2 += (-eta X2)^T @ gZ2
      #pragma unroll
      for (int kt=0;kt<2;kt++){
        v8s bfs[4];
        #pragma unroll
        for (int nt=0;nt<4;nt++) bfs[nt] = ld8(&GZ2t[(nt*16+l16)*68 + kt*32+q*8]);
        #pragma unroll
        for (int mi=0;mi<2;mi++){
          v8s af;
          #pragma unroll
          for (int j=0;j<8;j++){
            int jj=kt*32+q*8+j;
            af[j]=(short)fbf(-eta_s[jj]*bfu(X2s[jj*260 + (w*2+mi)*16+l16]));
          }
          #pragma unroll
          for (int nt=0;nt<4;nt++)
            w2r[mi][nt] = __builtin_amdgcn_mfma_f32_16x16x32_bf16(af, bfs[nt], w2r[mi][nt], 0,0,0);
        }
      }
    }
  }
}

extern "C" void kernel_launch(void* const* d_in, const int* in_sizes, int n_in,
                              void* d_out, int out_size, void* d_ws, size_t ws_size,
                              hipStream_t stream)
{
  const float* x_in   = (const float*)d_in[0];
  const float* ln1w   = (const float*)d_in[1];
  const float* ln1b   = (const float*)d_in[2];
  const float* awq    = (const float*)d_in[3];
  const float* awk    = (const float*)d_in[4];
  const float* awv    = (const float*)d_in[5];
  const float* awo    = (const float*)d_in[6];
  const float* wqw    = (const float*)d_in[7];
  const float* wqb    = (const float*)d_in[8];
  const float* wkw    = (const float*)d_in[9];
  const float* wkb    = (const float*)d_in[10];
  const float* wvw    = (const float*)d_in[11];
  const float* wvb    = (const float*)d_in[12];
  const float* wow    = (const float*)d_in[13];
  const float* wob    = (const float*)d_in[14];
  const float* W1in   = (const float*)d_in[15];
  const float* b1in   = (const float*)d_in[16];
  const float* W2in   = (const float*)d_in[17];
  const float* b2in   = (const float*)d_in[18];
  const float* tnw    = (const float*)d_in[19];
  const float* tnb    = (const float*)d_in[20];
  const float* lrw    = (const float*)d_in[21];
  const float* lrb    = (const float*)d_in[22];
  const float* pnw    = (const float*)d_in[23];
  const float* pnb    = (const float*)d_in[24];
  const float* galpha = (const float*)d_in[25];
  float* outp = (float*)d_out;
  char* ws = (char*)d_ws;
  const size_t MB = (size_t)1<<20;
  // f32 buffers
  float* bq  = (float*)(ws + 0*MB);       // TTT proj q (L5->L7)
  float* bk  = (float*)(ws + 16*MB);
  float* bv  = (float*)(ws + 32*MB);
  float* bo  = (float*)(ws + 64*MB);      // tout aliases here
  float* bxb = (float*)(ws + 80*MB);      // residual stream (L4->L6,L10)
  float* xqt = (float*)(ws + 96*MB);      // scan inputs (L7->L8)
  float* tgtp = (float*)(ws + 112*MB);
  unsigned short* xq_bf  = (unsigned short*)(ws + 128*MB);
  unsigned short* xk_bf  = (unsigned short*)(ws + 136*MB);
  float* etab = (float*)(ws + 144*MB);
  unsigned short* xkTe_bf = (unsigned short*)(ws + 48*MB);   // 48-56MB
  // bf16 weight scratch (56-64MB pocket, free until L8 writes bo at 64MB):
  unsigned short* wc0 = (unsigned short*)(ws + 56*MB);
  unsigned short* wc1 = (unsigned short*)(ws + 58*MB);
  unsigned short* wc2 = (unsigned short*)(ws + 60*MB);
  unsigned short* wc3 = (unsigned short*)(ws + 62*MB);
  // bf16 staging buffers, aliased into regions dead at their lifetime:
  unsigned short* bhh_bf  = (unsigned short*)(ws + 96*MB);   // L1->L2 (xqt written L7)
  unsigned short* bq_bf   = (unsigned short*)(ws + 128*MB);  // L2->L3 (xq_bf written L7)
  unsigned short* bk_bf   = (unsigned short*)(ws + 136*MB);  // L2->L3
  unsigned short* bv_bf   = (unsigned short*)(ws + 80*MB);   // L2->L3 (bxb written L4)
  unsigned short* bo_bf   = (unsigned short*)(ws + 112*MB);  // L3->L4 (tgtp written L7)
  unsigned short* bxb_bf  = (unsigned short*)(ws + 128*MB);  // L4->L5 (bq_bf dead after L3)
  unsigned short* bhh2_bf = (unsigned short*)(ws + 0*MB);    // L9->L10 (bq dead after L7)
  float* tout = bo;

  // W-convert #1: attn weights (awq,awk,awv,awo)
  wcvt_kernel<<<dim3(64,4),256,0,stream>>>(awq,awk,awv,awo, wc0,wc1,wc2,wc3);
  // L1: LN -> bf16 only
  ln_kernel<<<4096,256,0,stream>>>(x_in, ln1w, ln1b, nullptr, bhh_bf);
  // L2: fused attn-QKV gemm (bf16 outs only)
  gemm_kernel<<<dim3(24,32),256,0,stream>>>(bhh_bf, wc0,wc1,wc2,
      nullptr,nullptr,nullptr, nullptr, nullptr,
      nullptr,nullptr,nullptr, bq_bf,bk_bf,bv_bf);
  // L3: attention (bf16 in, bf16 out only)
  attn_kernel<<<1024,256,0,stream>>>(bq_bf,bk_bf,bv_bf, nullptr, bo_bf);
  // L4: wo gemm + residual -> bxb f32 + bf16
  gemm_kernel<<<dim3(8,32),256,0,stream>>>(bo_bf, wc3,wc3,wc3,
      nullptr,nullptr,nullptr, x_in, nullptr,
      bxb,bxb,bxb, bxb_bf,bxb_bf,bxb_bf);
  // W-convert #2: TTT weights (wqw,wkw,wvw,wow)
  wcvt_kernel<<<dim3(64,4),256,0,stream>>>(wqw,wkw,wvw,wow, wc0,wc1,wc2,wc3);
  // L5: fused TTT-QKV gemm (f32 outs for xqkv)
  gemm_kernel<<<dim3(24,32),256,0,stream>>>(bxb_bf, wc0,wc1,wc2,
      wqb,wkb,wvb, nullptr, nullptr,
      bq,bk,bv, nullptr,nullptr,nullptr);
  // L6: eta
  eta_kernel<<<1024,256,0,stream>>>(bxb, lrw, lrb, etab);
  // L7: xqkv staging
  xqkv_kernel<<<16384,256,0,stream>>>(bq,bk,bv,tnw,tnb,etab,xqt,tgtp,xq_bf,xk_bf,xkTe_bf);
  // L8: TTT scan (8 waves, 2/EU)
  scan_kernel<<<64,512,0,stream>>>(xqt,tgtp,xq_bf,xk_bf,xkTe_bf,etab,W1in,b1in,W2in,b2in,tnw,tnb,tout);
  // L9: post-scan LN -> bf16 only
  ln_kernel<<<4096,256,0,stream>>>(tout, pnw, pnb, nullptr, bhh2_bf);
  // L10: final gemm with gate + residual
  gemm_kernel<<<dim3(8,32),256,0,stream>>>(bhh2_bf, wc3,wc3,wc3,
      wob,wob,wob, bxb, galpha,
      outp,outp,outp, nullptr,nullptr,nullptr);
}

// Round 13
// 908.313 us; speedup vs baseline: 1.0231x; 1.0231x over previous
//
#include <hip/hip_runtime.h>

// Shapes (fixed): B=4 S=1024 D=1024 H=16 HD=64 C=64 NC=16 DFF=256
typedef short v8s __attribute__((ext_vector_type(8)));
typedef short v4s __attribute__((ext_vector_type(4)));
typedef float v4f __attribute__((ext_vector_type(4)));

__device__ __forceinline__ float bfu(unsigned short u){ return __uint_as_float(((unsigned)u)<<16); }
__device__ __forceinline__ unsigned short fbf(float f){
  unsigned u = __float_as_uint(f);
  u += 0x7fffu + ((u>>16)&1u);
  return (unsigned short)(u>>16);
}
__device__ __forceinline__ float wsum(float v){
  #pragma unroll
  for (int off=32; off>0; off>>=1) v += __shfl_xor(v, off, 64);
  return v;
}
__device__ __forceinline__ float clampv(float x){ return fminf(fmaxf(x, -1e8f), 1e8f); }
__device__ __forceinline__ float tanh_f(float x){
  x = fminf(fmaxf(x, -15.f), 15.f);
  float e = __expf(2.f*x);
  return (e-1.f)/(e+1.f);
}
__device__ __forceinline__ float gelu_f(float x){
  float t = tanh_f(0.79788456f*(x + 0.044715f*x*x*x));
  return 0.5f*x*(1.f+t);
}
__device__ __forceinline__ float gelu_bwd_f(float x){
  float t = tanh_f(0.79788456f*(x + 0.044715f*x*x*x));
  return 0.5f*x*(1.f-t*t)*(0.79788456f + 0.1070322243f*x*x) + 0.5f*(1.f+t);
}
__device__ __forceinline__ v8s ld8(const unsigned short* p){
  v4s lo = *(const v4s*)p, hi = *(const v4s*)(p+4);
  v8s r;
  r[0]=lo[0];r[1]=lo[1];r[2]=lo[2];r[3]=lo[3];
  r[4]=hi[0];r[5]=hi[1];r[6]=hi[2];r[7]=hi[3];
  return r;
}

// ---------------- f32 -> bf16 weight conversion, 4 matrices per launch ----------------
__global__ __launch_bounds__(256) void wcvt_kernel(
    const float* __restrict__ s0, const float* __restrict__ s1,
    const float* __restrict__ s2, const float* __restrict__ s3,
    unsigned short* __restrict__ d0, unsigned short* __restrict__ d1,
    unsigned short* __restrict__ d2, unsigned short* __restrict__ d3)
{
  int y = blockIdx.y;
  const float* s = y==0?s0:(y==1?s1:(y==2?s2:s3));
  unsigned short* d = y==0?d0:(y==1?d1:(y==2?d2:d3));
  int tid = blockIdx.x*256 + threadIdx.x;   // 16384 threads
  #pragma unroll 4
  for (int i=0;i<16;i++){
    size_t o = (size_t)i*65536 + (size_t)tid*4;
    float4 v = *(const float4*)&s[o];
    v4s p;
    p[0]=(short)fbf(v.x); p[1]=(short)fbf(v.y); p[2]=(short)fbf(v.z); p[3]=(short)fbf(v.w);
    *(v4s*)&d[o] = p;
  }
}

// ---------------- LayerNorm over D=1024, one block per row; optional f32/bf16 outs ----------------
__global__ __launch_bounds__(256) void ln_kernel(
    const float* __restrict__ X, const float* __restrict__ g,
    const float* __restrict__ bta, float* __restrict__ out,
    unsigned short* __restrict__ outbf)
{
  __shared__ float red[4];
  int row = blockIdx.x, t = threadIdx.x;
  const float* xr = X + (size_t)row*1024;
  float v[4];
  #pragma unroll
  for (int i=0;i<4;i++) v[i] = xr[t + i*256];
  float s = v[0]+v[1]+v[2]+v[3];
  s = wsum(s);
  if ((t&63)==0) red[t>>6]=s;
  __syncthreads();
  float mu = (red[0]+red[1]+red[2]+red[3])*(1.f/1024.f);
  float q=0.f;
  #pragma unroll
  for (int i=0;i<4;i++){ float dd=v[i]-mu; q+=dd*dd; }
  q = wsum(q);
  __syncthreads();
  if ((t&63)==0) red[t>>6]=q;
  __syncthreads();
  float var = (red[0]+red[1]+red[2]+red[3])*(1.f/1024.f);
  float rs = rsqrtf(var+1e-6f);
  #pragma unroll
  for (int i=0;i<4;i++){
    int c = t+i*256;
    float vv = (v[i]-mu)*rs*g[c] + bta[c];
    if (out)   out[(size_t)row*1024+c] = vv;
    if (outbf) outbf[(size_t)row*1024+c] = fbf(vv);
  }
}

// ---- MFMA GEMM (bf16 A, bf16 pre-converted weights), optionally 3-way fused along N.
// global_load_lds(16B) staging into linear [128][64] LDS with XOR swizzle; low VGPR
// -> __launch_bounds__(256,3): 3 blocks/CU so the 768-block fused launches are fully
// co-resident (no tail wave).
__global__ __launch_bounds__(256, 3) void gemm_kernel(
    const unsigned short* __restrict__ A_bf,
    const unsigned short* __restrict__ B0, const unsigned short* __restrict__ B1, const unsigned short* __restrict__ B2,
    const float* __restrict__ bias0, const float* __restrict__ bias1, const float* __restrict__ bias2,
    const float* __restrict__ res, const float* __restrict__ gate,
    float* __restrict__ out0, float* __restrict__ out1, float* __restrict__ out2,
    unsigned short* __restrict__ obf0, unsigned short* __restrict__ obf1, unsigned short* __restrict__ obf2)
{
  __shared__ __attribute__((aligned(16))) unsigned short a_lds[128*64];
  __shared__ __attribute__((aligned(16))) unsigned short b_lds[128*64];
  int t=threadIdx.x, w=t>>6, lane=t&63;
  int widx = blockIdx.x>>3;
  const unsigned short* Bw = widx==0?B0:(widx==1?B1:B2);
  const float* bias = widx==0?bias0:(widx==1?bias1:bias2);
  float* out        = widx==0?out0:(widx==1?out1:out2);
  unsigned short* obf = widx==0?obf0:(widx==1?obf1:obf2);
  int gm = blockIdx.y*128, gn = (blockIdx.x&7)*128;
  int wm=(w>>1)*64, wn=(w&1)*64, lr=lane&15;
  int rl = lane>>3, j0 = lane&7;          // staging: row-in-chunk, 16B-chunk index
  int qb = (lane>>4)*16;                  // read: byte offset of k-quad within 64B half
  v4f acc[4][4];
  #pragma unroll
  for (int i=0;i<4;i++)
    #pragma unroll
    for (int j=0;j<4;j++){ v4f z={0.f,0.f,0.f,0.f}; acc[i][j]=z; }
  for (int kk=0; kk<1024; kk+=64){
    __syncthreads();
    #pragma unroll
    for (int c=0;c<4;c++){
      int r = w*32 + c*8 + rl;                       // LDS row 0..127
      int js = (j0 ^ (r&7))*16;                      // swizzled source byte-in-row
      const char* ga = (const char*)A_bf + ((size_t)(gm+r)*1024 + kk)*2 + js;
      const char* gb = (const char*)Bw  + ((size_t)(gn+r)*1024 + kk)*2 + js;
      __builtin_amdgcn_global_load_lds(
          (const __attribute__((address_space(1))) void*)ga,
          (__attribute__((address_space(3))) void*)&a_lds[(w*32+c*8)*64], 16, 0, 0);
      __builtin_amdgcn_global_load_lds(
          (const __attribute__((address_space(1))) void*)gb,
          (__attribute__((address_space(3))) void*)&b_lds[(w*32+c*8)*64], 16, 0, 0);
    }
    __syncthreads();
    #pragma unroll
    for (int k2=0;k2<2;k2++){
      v8s af[4], bfr[4];
      #pragma unroll
      for (int i=0;i<4;i++){
        int R = wm+i*16+lr;
        int byt = (k2*64 + qb) ^ ((R&7)<<4);
        af[i] = ld8((const unsigned short*)((const char*)&a_lds[R*64] + byt));
      }
      #pragma unroll
      for (int j=0;j<4;j++){
        int R = wn+j*16+lr;
        int byt = (k2*64 + qb) ^ ((R&7)<<4);
        bfr[j] = ld8((const unsigned short*)((const char*)&b_lds[R*64] + byt));
      }
      #pragma unroll
      for (int i=0;i<4;i++)
        #pragma unroll
        for (int j=0;j<4;j++)
          acc[i][j] = __builtin_amdgcn_mfma_f32_16x16x32_bf16(af[i], bfr[j], acc[i][j], 0,0,0);
    }
  }
  int quad = lane>>4;
  #pragma unroll
  for (int j=0;j<4;j++){
    int gc = gn + wn + j*16 + lr;
    float bval = bias ? bias[gc] : 0.f;
    float gval = gate ? tanh_f(gate[gc]) : 1.f;
    #pragma unroll
    for (int i=0;i<4;i++){
      #pragma unroll
      for (int r=0;r<4;r++){
        int grow = gm + wm + i*16 + quad*4 + r;
        float v = (acc[i][j][r] + bval)*gval;
        if (res) v += res[(size_t)grow*1024 + gc];
        size_t oi = (size_t)grow*1024 + gc;
        if (out) out[oi] = v;
        if (obf) obf[oi] = fbf(v);
      }
    }
  }
}

// ---------------- MFMA flash attention (bf16 in), block = (b,h,q-tile of 64) ----------------
__global__ __launch_bounds__(256) void attn_kernel(
    const unsigned short* __restrict__ Q, const unsigned short* __restrict__ K,
    const unsigned short* __restrict__ V, float* __restrict__ O,
    unsigned short* __restrict__ Obf)
{
  __shared__ __attribute__((aligned(16))) unsigned short q_l[64*68];
  __shared__ __attribute__((aligned(16))) unsigned short k_l[64*68];
  __shared__ __attribute__((aligned(16))) unsigned short vt_l[64*68]; // V^T [d][j]
  __shared__ __attribute__((aligned(16))) unsigned short p_l[64*68];
  int t=threadIdx.x, w=t>>6, lane=t&63, q=lane>>4, l16=lane&15;
  int qt = blockIdx.x & 15, bh = blockIdx.x >> 4;
  int b = bh >> 4, h = bh & 15;
  const size_t base = ((size_t)b*1024)*1024 + (size_t)h*64;
  #pragma unroll
  for (int pass=0;pass<4;pass++){
    int slot=t+pass*256, row=slot>>4, c4=(slot&15)*4;
    v4s qv = *(const v4s*)&Q[base + (size_t)(qt*64+row)*1024 + c4];
    *(v4s*)&q_l[row*68+c4]=qv;
  }
  float mi[4], li[4];
  v4f o[4];
  #pragma unroll
  for (int r=0;r<4;r++){ mi[r]=-1e30f; li[r]=0.f; }
  #pragma unroll
  for (int dtn=0;dtn<4;dtn++){ v4f z={0.f,0.f,0.f,0.f}; o[dtn]=z; }
  for (int kt=0; kt<=qt; kt++){
    __syncthreads();
    #pragma unroll
    for (int pass=0;pass<4;pass++){
      int slot=t+pass*256, row=slot>>4, c4=(slot&15)*4;
      v4s kv = *(const v4s*)&K[base + (size_t)(kt*64+row)*1024 + c4];
      *(v4s*)&k_l[row*68+c4]=kv;
      v4s vv = *(const v4s*)&V[base + (size_t)(kt*64+row)*1024 + c4];
      vt_l[(c4+0)*68+row]=(unsigned short)vv[0];
      vt_l[(c4+1)*68+row]=(unsigned short)vv[1];
      vt_l[(c4+2)*68+row]=(unsigned short)vv[2];
      vt_l[(c4+3)*68+row]=(unsigned short)vv[3];
    }
    __syncthreads();
    // S = Q@K^T (wave rows w*16..+15)
    v4f s[4];
    #pragma unroll
    for (int nt=0;nt<4;nt++){ v4f z={0.f,0.f,0.f,0.f}; s[nt]=z; }
    #pragma unroll
    for (int k2=0;k2<2;k2++){
      v8s af = ld8(&q_l[(w*16+l16)*68 + k2*32+q*8]);
      #pragma unroll
      for (int nt=0;nt<4;nt++){
        v8s bf = ld8(&k_l[(nt*16+l16)*68 + k2*32+q*8]);
        s[nt] = __builtin_amdgcn_mfma_f32_16x16x32_bf16(af, bf, s[nt], 0,0,0);
      }
    }
    bool diag = (kt==qt);
    #pragma unroll
    for (int r=0;r<4;r++){
      int row_l = w*16+q*4+r;
      float mx=-1e30f;
      #pragma unroll
      for (int nt=0;nt<4;nt++){
        int col=nt*16+l16;
        float sv = s[nt][r]*0.125f;
        if (diag && col>row_l) sv=-1e30f;
        s[nt][r]=sv; mx=fmaxf(mx,sv);
      }
      #pragma unroll
      for (int off=1;off<16;off<<=1) mx=fmaxf(mx,__shfl_xor(mx,off,16));
      float mnew=fmaxf(mi[r],mx);
      float aexp=__expf(mi[r]-mnew);
      float ps=0.f;
      #pragma unroll
      for (int nt=0;nt<4;nt++){
        float p=__expf(s[nt][r]-mnew);
        s[nt][r]=p; ps+=p;
      }
      #pragma unroll
      for (int off=1;off<16;off<<=1) ps+=__shfl_xor(ps,off,16);
      li[r]=li[r]*aexp+ps; mi[r]=mnew;
      #pragma unroll
      for (int dtn=0;dtn<4;dtn++) o[dtn][r]*=aexp;
      #pragma unroll
      for (int nt=0;nt<4;nt++) p_l[row_l*68 + nt*16+l16]=fbf(s[nt][r]);
    }
    __syncthreads();
    // O += P@V
    #pragma unroll
    for (int k2=0;k2<2;k2++){
      v8s af = ld8(&p_l[(w*16+l16)*68 + k2*32+q*8]);
      #pragma unroll
      for (int dtn=0;dtn<4;dtn++){
        v8s bf = ld8(&vt_l[(dtn*16+l16)*68 + k2*32+q*8]);
        o[dtn] = __builtin_amdgcn_mfma_f32_16x16x32_bf16(af, bf, o[dtn], 0,0,0);
      }
    }
  }
  #pragma unroll
  for (int dtn=0;dtn<4;dtn++)
    #pragma unroll
    for (int r=0;r<4;r++){
      float vv = o[dtn][r]/li[r];
      size_t oi = base + (size_t)(qt*64+w*16+q*4+r)*1024 + dtn*16+l16;
      if (O)   O[oi] = vv;
      if (Obf) Obf[oi] = fbf(vv);
    }
}

// ------- XQ/XK normalize + target fuse; write TTT layouts. wave = (b,s,h) -------
__global__ __launch_bounds__(256) void xqkv_kernel(
    const float* __restrict__ XQ, const float* __restrict__ XK,
    const float* __restrict__ XV, const float* __restrict__ nw,
    const float* __restrict__ nb, const float* __restrict__ eta,
    float* __restrict__ xqt, float* __restrict__ tgtp,
    unsigned short* __restrict__ xq_bf, unsigned short* __restrict__ xk_bf,
    unsigned short* __restrict__ xkTe_bf)
{
  int gw = (int)((blockIdx.x*256 + threadIdx.x)>>6);
  int lane = threadIdx.x & 63;
  int h = gw & 15, s = (gw>>4)&1023, b = gw>>14;
  size_t src = ((size_t)(b*1024+s))*1024 + h*64 + lane;
  float xq = XQ[src], xk = XK[src], xv = XV[src];
  float nq = sqrtf(wsum(xq*xq));
  float nk = sqrtf(wsum(xk*xk));
  float xqn = xq / fmaxf(nq, 1e-12f);
  float xkn = xk / fmaxf(nk, 1e-12f);
  float mu = wsum(xv)*(1.f/64.f);
  float xm = xv-mu;
  float var = wsum(xm*xm)*(1.f/64.f);
  float xvh = xm*rsqrtf(var+1e-6f);
  float tg = nw[h*64+lane]*xvh + nb[h*64+lane];   // xvn - xkn exactly
  float et = eta[((size_t)(b*16+h))*1024 + s];
  size_t dst = ((size_t)(b*16+h)*1024 + s)*64 + lane;
  xq_bf[dst]=fbf(xqn); xk_bf[dst]=fbf(xkn);
  xkTe_bf[((size_t)(b*16+h)*64 + lane)*1024 + s] = fbf(-et*xkn);
  int n_ = s>>6, row = s&63;
  int wv = row>>4, qq = (row>>2)&3, rr = row&3;
  int nt_ = lane>>4, l16_ = lane&15;
  int tt = wv*64 + qq*16 + l16_;
  size_t dst2 = (size_t)(b*16+h)*65536 + (size_t)n_*4096 + (size_t)tt*16 + nt_*4 + rr;
  xqt[dst2]=xqn; tgtp[dst2]=tg;
}

// ------- eta[b,h,s] = sigmoid(x[b,s,:]·lr_w[h,:] + lr_b[h]) / 64. wave = (b,s) -------
__global__ __launch_bounds__(256) void eta_kernel(
    const float* __restrict__ Xb, const float* __restrict__ lrw,
    const float* __restrict__ lrb, float* __restrict__ eta)
{
  int gw = (int)((blockIdx.x*256 + threadIdx.x)>>6);
  int lane = threadIdx.x & 63;
  int s = gw & 1023, b = gw >> 10;
  const float* xrow = Xb + ((size_t)(b*1024+s))*1024;
  float xr[16];
  #pragma unroll
  for (int i=0;i<16;i++) xr[i] = xrow[i*64+lane];
  #pragma unroll 1
  for (int h=0;h<16;h++){
    const float* wr = lrw + h*1024;
    float acc=0.f;
    #pragma unroll
    for (int i=0;i<16;i++) acc += xr[i]*wr[i*64+lane];
    acc = wsum(acc);
    if (lane==h){
      float vv = acc + lrb[h];
      float sg = 1.f/(1.f+__expf(-vv));
      eta[((size_t)(b*16+h))*1024 + s] = sg*(1.f/64.f);
    }
  }
}

// ---------------- TTT scan (MFMA, LDS-resident), 512 threads = 8 waves ----------------
// Frozen at round-8's measured-best form (489-493us): register-diet gbp/x2bp,
// two-barrier LN2, per-phase loads, ln_scr stride 8.
__global__ __launch_bounds__(512, 2) __attribute__((amdgpu_waves_per_eu(2, 2)))
void scan_kernel(
    const float* __restrict__ xqt, const float* __restrict__ tgtp,
    const unsigned short* __restrict__ xq_bf, const unsigned short* __restrict__ xk_bf,
    const unsigned short* __restrict__ xkTe_bf, const float* __restrict__ eta,
    const float* __restrict__ W1in, const float* __restrict__ b1in,
    const float* __restrict__ W2in, const float* __restrict__ b2in,
    const float* __restrict__ nw, const float* __restrict__ nb,
    float* __restrict__ tout)
{
  __shared__ __attribute__((aligned(16))) unsigned short W1t[256*68];  // W1^T [n][k]
  __shared__ __attribute__((aligned(16))) unsigned short W2T[64*260];  // W2^T [d][k]
  __shared__ __attribute__((aligned(16))) unsigned short X2s[64*260];  // X2 [m][n]
  __shared__ __attribute__((aligned(16))) unsigned short GXu[256*68];  // GZ1t [n][j] / X2b [m][n](260)
  __shared__ __attribute__((aligned(16))) unsigned short GZ2t[64*68];  // gZ2^T [d][j]
  __shared__ __attribute__((aligned(16))) unsigned short AMs[64*68];   // -tril(eta*(A+1)) [m][j]
  __shared__ float ln_scr[64*8];
  __shared__ float eta_s[64], b1_s[256], b2_s[64], nw_s[64], nb_s[64];

  const int t=threadIdx.x, w=t>>6, lane=t&63, q=lane>>4, l16=lane&15;
  const int bh=blockIdx.x, b=bh>>4, h=bh&15;
  const int mt=w>>1, half=w&1, nh=half*8, nh4=half*2;
  const float* xq_g  = xqt  + (size_t)bh*65536;
  const float* tgt_g = tgtp + (size_t)bh*65536;
  const unsigned short* xqb_g = xq_bf  + (size_t)bh*65536;
  const unsigned short* xkb_g = xk_bf  + (size_t)bh*65536;
  const unsigned short* xkT_g = xkTe_bf + (size_t)bh*65536;
  const float* eta_g = eta + (size_t)bh*1024;

  // W1 masters (C-frag): rows mt*16+q*4+r, cols (nh+nt)*16+l16
  v4f w1r[8];
  #pragma unroll
  for (int nt=0;nt<8;nt++){
    int col=(nh+nt)*16+l16;
    #pragma unroll
    for (int r=0;r<4;r++) w1r[nt][r] = W1in[h*16384 + (mt*16+q*4+r)*256 + col];
  }
  // W2 masters: rows (w*2+mi)*16+q*4+r, cols nt*16+l16
  v4f w2r[2][4];
  #pragma unroll
  for (int mi=0;mi<2;mi++)
    #pragma unroll
    for (int nt=0;nt<4;nt++){
      int col=nt*16+l16;
      #pragma unroll
      for (int r=0;r<4;r++) w2r[mi][nt][r] = W2in[h*16384 + ((w*2+mi)*16+q*4+r)*64 + col];
    }
  if (t<256) b1_s[t]=b1in[h*256+t];
  if (t<64){ b2_s[t]=b2in[h*64+t]; nw_s[t]=nw[h*64+t]; nb_s[t]=nb[h*64+t]; }

  float bacc=0.f, bacc2=0.f;   // deferred bias updates

  for (int n=0;n<16;n++){
    // prefetch this step's A-fragments (global, safe pre-barrier)
    v8s xkf[2], xqf[2];
    #pragma unroll
    for (int kt=0;kt<2;kt++){
      xkf[kt] = ld8(&xkb_g[(size_t)n*4096 + (mt*16+l16)*64 + kt*32+q*8]);
      xqf[kt] = ld8(&xqb_g[(size_t)n*4096 + (mt*16+l16)*64 + kt*32+q*8]);
    }
    __syncthreads();                                        // B1: prev-step readers done
    if (t<256) b1_s[t] -= bacc;
    if (t<64){ b2_s[t] -= bacc2; eta_s[t]=eta_g[n*64+t]; }
    // ---- stage bf16 W copies (transposed) ----
    #pragma unroll
    for (int nt=0;nt<8;nt++){
      int col=(nh+nt)*16+l16;
      #pragma unroll
      for (int pr=0;pr<2;pr++){
        unsigned lo=fbf(w1r[nt][pr*2]), hi=fbf(w1r[nt][pr*2+1]);
        *(unsigned*)&W1t[col*68 + mt*16+q*4 + pr*2] = lo | (hi<<16);
      }
    }
    #pragma unroll
    for (int mi=0;mi<2;mi++)
      #pragma unroll
      for (int nt=0;nt<4;nt++){
        int col=nt*16+l16;
        #pragma unroll
        for (int pr=0;pr<2;pr++){
          unsigned lo=fbf(w2r[mi][nt][pr*2]), hi=fbf(w2r[mi][nt][pr*2+1]);
          *(unsigned*)&W2T[col*260 + (w*2+mi)*16+q*4 + pr*2] = lo | (hi<<16);
        }
      }
    __syncthreads();                                        // B2: staging visible

    // ---- P1: Z1 = xk@W1 + b1; X2 -> X2s; gelu' packed bf16 -> gbp. A4 -> AMs. ----
    unsigned gbp[16];
    {
      v4f a1[8];
      #pragma unroll
      for (int i=0;i<8;i++){ v4f z={0.f,0.f,0.f,0.f}; a1[i]=z; }
      #pragma unroll
      for (int kt=0;kt<2;kt++){
        #pragma unroll
        for (int nt=0;nt<8;nt++){
          v8s bf = ld8(&W1t[((nh+nt)*16+l16)*68 + kt*32+q*8]);
          a1[nt] = __builtin_amdgcn_mfma_f32_16x16x32_bf16(xkf[kt], bf, a1[nt], 0,0,0);
        }
      }
      #pragma unroll
      for (int nt=0;nt<8;nt++){
        int col=(nh+nt)*16+l16; float bb=b1_s[col];
        float zz[4];
        #pragma unroll
        for (int r=0;r<4;r++){
          float z=clampv(a1[nt][r]+bb); zz[r]=z;
          X2s[(mt*16+q*4+r)*260+col]=fbf(clampv(gelu_f(z)));
        }
        #pragma unroll
        for (int pr=0;pr<2;pr++)
          gbp[nt*2+pr] = (unsigned)fbf(gelu_bwd_f(zz[pr*2+0]))
                       | ((unsigned)fbf(gelu_bwd_f(zz[pr*2+1]))<<16);
      }
    }
    {
      v4f a4[2];
      #pragma unroll
      for (int i=0;i<2;i++){ v4f z={0.f,0.f,0.f,0.f}; a4[i]=z; }
      #pragma unroll
      for (int kt=0;kt<2;kt++){
        #pragma unroll
        for (int nt=0;nt<2;nt++){
          v8s bf = ld8(&xkb_g[(size_t)n*4096 + ((nh4+nt)*16+l16)*64 + kt*32+q*8]);
          a4[nt] = __builtin_amdgcn_mfma_f32_16x16x32_bf16(xqf[kt], bf, a4[nt], 0,0,0);
        }
      }
      #pragma unroll
      for (int nt=0;nt<2;nt++){
        int col=(nh4+nt)*16+l16;
        float ec=eta_s[col];
        #pragma unroll
        for (int r=0;r<4;r++){
          int row=mt*16+q*4+r;
          AMs[row*68+col] = (col<=row) ? fbf(-ec*(a4[nt][r]+1.f)) : (unsigned short)0;
        }
      }
    }

    // ---- P2: Z2 = X2@W2 + b2 ; LN2 (cross-half via ln_scr) -> GZ2t ----
    {
      const float* tc = tgt_g + (size_t)n*4096 + (size_t)(mt*64+q*16+l16)*16 + nh4*4;
      float4 ta=*(const float4*)tc, tb=*(const float4*)(tc+4);
      float tgs[8]={ta.x,ta.y,ta.z,ta.w,tb.x,tb.y,tb.z,tb.w};
      v4f a2[2];
      #pragma unroll
      for (int i=0;i<2;i++){ v4f z={0.f,0.f,0.f,0.f}; a2[i]=z; }
      #pragma unroll
      for (int kt=0;kt<8;kt++){
        v8s af = ld8(&X2s[(mt*16+l16)*260 + kt*32+q*8]);
        #pragma unroll
        for (int nt=0;nt<2;nt++){
          v8s bf = ld8(&W2T[((nh4+nt)*16+l16)*260 + kt*32+q*8]);
          a2[nt] = __builtin_amdgcn_mfma_f32_16x16x32_bf16(af, bf, a2[nt], 0,0,0);
        }
      }
      float z2[2][4];
      #pragma unroll
      for (int nt=0;nt<2;nt++){
        float bb=b2_s[(nh4+nt)*16+l16];
        #pragma unroll
        for (int r=0;r<4;r++) z2[nt][r]=clampv(a2[nt][r]+bb);
      }
      #pragma unroll
      for (int r=0;r<4;r++){
        float s1v=z2[0][r]+z2[1][r];
        float s2v=z2[0][r]*z2[0][r]+z2[1][r]*z2[1][r];
        #pragma unroll
        for (int off=1;off<16;off<<=1){ s1v+=__shfl_xor(s1v,off,16); s2v+=__shfl_xor(s2v,off,16); }
        if (l16==0){ int row=mt*16+q*4+r; ln_scr[row*8+half]=s1v; ln_scr[row*8+2+half]=s2v; }
      }
      __syncthreads();                                      // B3
      float muv[4], istd[4];
      #pragma unroll
      for (int r=0;r<4;r++){
        int row=mt*16+q*4+r;
        float S1=ln_scr[row*8+0]+ln_scr[row*8+1];
        float S2=ln_scr[row*8+2]+ln_scr[row*8+3];
        float mu=S1*(1.f/64.f);
        float var=fmaxf(S2*(1.f/64.f)-mu*mu, 0.f);
        muv[r]=mu; istd[r]=rsqrtf(var+1e-6f);
      }
      float xh[2][4], gh[2][4];
      #pragma unroll
      for (int nt=0;nt<2;nt++){
        int col=(nh4+nt)*16+l16;
        float gw_=nw_s[col], gb_=nb_s[col];
        #pragma unroll
        for (int r=0;r<4;r++){
          float x_=(z2[nt][r]-muv[r])*istd[r];
          float tgv = tgs[nt*4+r];
          xh[nt][r]=x_;
          gh[nt][r]=(gw_*x_+gb_-tgv)*gw_;
        }
      }
      #pragma unroll
      for (int r=0;r<4;r++){
        float t1=gh[0][r]+gh[1][r];
        float t2=gh[0][r]*xh[0][r]+gh[1][r]*xh[1][r];
        #pragma unroll
        for (int off=1;off<16;off<<=1){ t1+=__shfl_xor(t1,off,16); t2+=__shfl_xor(t2,off,16); }
        if (l16==0){ int row=mt*16+q*4+r; ln_scr[row*8+4+half]=t1; ln_scr[row*8+6+half]=t2; }
      }
      __syncthreads();                                      // B4
      #pragma unroll
      for (int nt=0;nt<2;nt++){
        int col=(nh4+nt)*16+l16;
        #pragma unroll
        for (int pr=0;pr<2;pr++){
          unsigned pk[2];
          #pragma unroll
          for (int k2=0;k2<2;k2++){
            int r=pr*2+k2;
            int row=mt*16+q*4+r;
            float G1s=ln_scr[row*8+4]+ln_scr[row*8+5];
            float G2s=ln_scr[row*8+6]+ln_scr[row*8+7];
            float gz=(64.f*gh[nt][r]-G1s-xh[nt][r]*G2s)*istd[r]*(1.f/64.f);
            pk[k2]=fbf(clampv(gz));
          }
          *(unsigned*)&GZ2t[col*68 + mt*16+q*4 + pr*2] = pk[0] | (pk[1]<<16);
        }
      }
    }
    __syncthreads();                                        // B5: GZ2t (both halves) visible

    // ---- P3: gZ1 = (gZ2@W2^T) * gelu'(Z1) -> GZ1t [n][j] ----
    {
      v4f a3[8];
      #pragma unroll
      for (int i=0;i<8;i++){ v4f z={0.f,0.f,0.f,0.f}; a3[i]=z; }
      #pragma unroll
      for (int kt=0;kt<2;kt++){
        v8s af;
        #pragma unroll
        for (int j=0;j<8;j++) af[j]=(short)GZ2t[(kt*32+q*8+j)*68 + mt*16+l16];
        #pragma unroll
        for (int nt=0;nt<8;nt++){
          int nb0=(nh+nt)*16+l16;
          v8s bf;
          #pragma unroll
          for (int j=0;j<8;j++) bf[j]=(short)W2T[(kt*32+q*8+j)*260 + nb0];
          a3[nt] = __builtin_amdgcn_mfma_f32_16x16x32_bf16(af, bf, a3[nt], 0,0,0);
        }
      }
      #pragma unroll
      for (int nt=0;nt<8;nt++){
        int col=(nh+nt)*16+l16;
        #pragma unroll
        for (int pr=0;pr<2;pr++){
          float d0=bfu((unsigned short)(gbp[nt*2+pr]&0xffffu));
          float d1=bfu((unsigned short)(gbp[nt*2+pr]>>16));
          float g0=clampv(a3[nt][pr*2+0]*d0);
          float g1=clampv(a3[nt][pr*2+1]*d1);
          unsigned lo=fbf(g0), hi=fbf(g1);
          *(unsigned*)&GXu[col*68 + mt*16+q*4 + pr*2] = lo | (hi<<16);
        }
      }
    }
    __syncthreads();                                        // B6: GZ1t visible

    // ---- P5: Z1b = xq@W1 + AMs@gZ1 + b1 ; H1 in-place: W1 += (-eta xk)^T @ gZ1 ;
    //      then compress X2b = fbf(gelu(Z1b+b1)) into x2bp BEFORE the barrier. ----
    unsigned x2bp[16];
    {
      float p0=0.f,p1=0.f,p2=0.f,p3=0.f;
      if (t<256){
        #pragma unroll
        for (int j4=0;j4<16;j4++){
          v4s v=*(const v4s*)&GXu[t*68+j4*4];
          p0 += eta_s[j4*4+0]*bfu((unsigned short)v[0]);
          p1 += eta_s[j4*4+1]*bfu((unsigned short)v[1]);
          p2 += eta_s[j4*4+2]*bfu((unsigned short)v[2]);
          p3 += eta_s[j4*4+3]*bfu((unsigned short)v[3]);
        }
      }
      bacc=(p0+p1)+(p2+p3);
      v8s xef[2];
      #pragma unroll
      for (int kt=0;kt<2;kt++)
        xef[kt] = ld8(&xkT_g[(size_t)(mt*16+l16)*1024 + n*64 + kt*32+q*8]);
      v4f a5[8];
      #pragma unroll
      for (int i=0;i<8;i++){ v4f z={0.f,0.f,0.f,0.f}; a5[i]=z; }
      #pragma unroll
      for (int kt=0;kt<2;kt++){
        #pragma unroll
        for (int nt=0;nt<8;nt++){
          v8s bf = ld8(&W1t[((nh+nt)*16+l16)*68 + kt*32+q*8]);
          a5[nt] = __builtin_amdgcn_mfma_f32_16x16x32_bf16(xqf[kt], bf, a5[nt], 0,0,0);
        }
      }
      #pragma unroll
      for (int kt=0;kt<2;kt++){
        v8s afA = ld8(&AMs[(mt*16+l16)*68 + kt*32+q*8]);
        #pragma unroll
        for (int nt=0;nt<8;nt++){
          v8s bf = ld8(&GXu[((nh+nt)*16+l16)*68 + kt*32+q*8]);
          a5[nt] = __builtin_amdgcn_mfma_f32_16x16x32_bf16(afA, bf, a5[nt], 0,0,0);
          w1r[nt] = __builtin_amdgcn_mfma_f32_16x16x32_bf16(xef[kt], bf, w1r[nt], 0,0,0);
        }
      }
      #pragma unroll
      for (int nt=0;nt<8;nt++){
        float bb=b1_s[(nh+nt)*16+l16];
        #pragma unroll
        for (int pr=0;pr<2;pr++){
          float z0=clampv(a5[nt][pr*2+0]+bb);
          float z1=clampv(a5[nt][pr*2+1]+bb);
          x2bp[nt*2+pr] = (unsigned)fbf(clampv(gelu_f(z0)))
                        | ((unsigned)fbf(clampv(gelu_f(z1)))<<16);
        }
      }
    }
    __syncthreads();                                        // B7: GXu/AMs reads done

    // ---- X2b (packed) -> GXu row-major [m][n](260) ----
    #pragma unroll
    for (int nt=0;nt<8;nt++){
      int col=(nh+nt)*16+l16;
      #pragma unroll
      for (int pr=0;pr<2;pr++){
        int row0=mt*16+q*4+pr*2;
        GXu[row0*260+col]     = (unsigned short)(x2bp[nt*2+pr]&0xffffu);
        GXu[(row0+1)*260+col] = (unsigned short)(x2bp[nt*2+pr]>>16);
      }
    }
    __syncthreads();                                        // B8: X2b visible

    // ---- P6: AMs = -tril(eta_j*(X2b@X2^T + 1)) ; b2 colsum (deferred) ----
    {
      float p0=0.f,p1=0.f,p2=0.f,p3=0.f;
      if (t<64){
        #pragma unroll
        for (int j4=0;j4<16;j4++){
          v4s v=*(const v4s*)&GZ2t[t*68+j4*4];
          p0 += eta_s[j4*4+0]*bfu((unsigned short)v[0]);
          p1 += eta_s[j4*4+1]*bfu((unsigned short)v[1]);
          p2 += eta_s[j4*4+2]*bfu((unsigned short)v[2]);
          p3 += eta_s[j4*4+3]*bfu((unsigned short)v[3]);
        }
      }
      bacc2=(p0+p1)+(p2+p3);
      v4f a7[2];
      #pragma unroll
      for (int i=0;i<2;i++){ v4f z={0.f,0.f,0.f,0.f}; a7[i]=z; }
      #pragma unroll
      for (int kt=0;kt<8;kt++){
        v8s af = ld8(&GXu[(mt*16+l16)*260 + kt*32+q*8]);   // X2b
        #pragma unroll
        for (int nt=0;nt<2;nt++){
          v8s bf = ld8(&X2s[((nh4+nt)*16+l16)*260 + kt*32+q*8]);
          a7[nt] = __builtin_amdgcn_mfma_f32_16x16x32_bf16(af, bf, a7[nt], 0,0,0);
        }
      }
      #pragma unroll
      for (int nt=0;nt<2;nt++){
        int col=(nh4+nt)*16+l16;
        float ec=eta_s[col];
        #pragma unroll
        for (int r=0;r<4;r++){
          int row=mt*16+q*4+r;
          AMs[row*68+col] = (col<=row) ? fbf(-ec*(a7[nt][r]+1.f)) : (unsigned short)0;
        }
      }
    }
    __syncthreads();                                        // B9: AMs visible

    // ---- P7: Z2b = X2b@W2 + AMs@gZ2 + b2 ; LN7 -> tout ; H2 in-place ----
    {
      const float* xc = xq_g + (size_t)n*4096 + (size_t)(mt*64+q*16+l16)*16 + nh4*4;
      float4 xa=*(const float4*)xc, xb=*(const float4*)(xc+4);
      float xqs[8]={xa.x,xa.y,xa.z,xa.w,xb.x,xb.y,xb.z,xb.w};
      v4f a8[2];
      #pragma unroll
      for (int i=0;i<2;i++){ v4f z={0.f,0.f,0.f,0.f}; a8[i]=z; }
      float b2old[2];
      #pragma unroll
      for (int nt=0;nt<2;nt++) b2old[nt]=b2_s[(nh4+nt)*16+l16];
      #pragma unroll
      for (int kt=0;kt<8;kt++){
        v8s af = ld8(&GXu[(mt*16+l16)*260 + kt*32+q*8]);   // X2b
        #pragma unroll
        for (int nt=0;nt<2;nt++){
          v8s bf = ld8(&W2T[((nh4+nt)*16+l16)*260 + kt*32+q*8]);
          a8[nt] = __builtin_amdgcn_mfma_f32_16x16x32_bf16(af, bf, a8[nt], 0,0,0);
        }
      }
      #pragma unroll
      for (int kt=0;kt<2;kt++){
        v8s afm = ld8(&AMs[(mt*16+l16)*68 + kt*32+q*8]);
        #pragma unroll
        for (int nt=0;nt<2;nt++){
          v8s bf = ld8(&GZ2t[((nh4+nt)*16+l16)*68 + kt*32+q*8]);
          a8[nt] = __builtin_amdgcn_mfma_f32_16x16x32_bf16(afm, bf, a8[nt], 0,0,0);
        }
      }
      float z2b[2][4];
      #pragma unroll
      for (int nt=0;nt<2;nt++)
        #pragma unroll
        for (int r=0;r<4;r++) z2b[nt][r]=clampv(a8[nt][r]+b2old[nt]);
      #pragma unroll
      for (int r=0;r<4;r++){
        float s1v=z2b[0][r]+z2b[1][r];
        float s2v=z2b[0][r]*z2b[0][r]+z2b[1][r]*z2b[1][r];
        #pragma unroll
        for (int off=1;off<16;off<<=1){ s1v+=__shfl_xor(s1v,off,16); s2v+=__shfl_xor(s2v,off,16); }
        if (l16==0){ int row=mt*16+q*4+r; ln_scr[row*8+half]=s1v; ln_scr[row*8+2+half]=s2v; }
      }
      __syncthreads();                                      // B10
      #pragma unroll
      for (int r=0;r<4;r++){
        int row=mt*16+q*4+r;
        float S1=ln_scr[row*8+0]+ln_scr[row*8+1];
        float S2=ln_scr[row*8+2]+ln_scr[row*8+3];
        float mu=S1*(1.f/64.f);
        float var=fmaxf(S2*(1.f/64.f)-mu*mu, 0.f);
        float istd=rsqrtf(var+1e-6f);
        #pragma unroll
        for (int nt=0;nt<2;nt++){
          int col=(nh4+nt)*16+l16;
          float x_=(z2b[nt][r]-mu)*istd;
          float outv = xqs[nt*4+r] + x_*nw_s[col] + nb_s[col];
          tout[((size_t)(b*1024 + n*64 + row))*1024 + h*64 + col] = outv;
        }
      }
      // H2 in-place: W2 += (-eta X2)^T @ gZ2
      #pragma unroll
      for (int kt=0;kt<2;kt++){
        v8s bfs[4];
        #pragma unroll
        for (int nt=0;nt<4;nt++) bfs[nt] = ld8(&GZ2t[(nt*16+l16)*68 + kt*32+q*8]);
        #pragma unroll
        for (int mi=0;mi<2;mi++){
          v8s af;
          #pragma unroll
          for (int j=0;j<8;j++){
            int jj=kt*32+q*8+j;
            af[j]=(short)fbf(-eta_s[jj]*bfu(X2s[jj*260 + (w*2+mi)*16+l16]));
          }
          #pragma unroll
          for (int nt=0;nt<4;nt++)
            w2r[mi][nt] = __builtin_amdgcn_mfma_f32_16x16x32_bf16(af, bfs[nt], w2r[mi][nt], 0,0,0);
        }
      }
    }
  }
}

extern "C" void kernel_launch(void* const* d_in, const int* in_sizes, int n_in,
                              void* d_out, int out_size, void* d_ws, size_t ws_size,
                              hipStream_t stream)
{
  const float* x_in   = (const float*)d_in[0];
  const float* ln1w   = (const float*)d_in[1];
  const float* ln1b   = (const float*)d_in[2];
  const float* awq    = (const float*)d_in[3];
  const float* awk    = (const float*)d_in[4];
  const float* awv    = (const float*)d_in[5];
  const float* awo    = (const float*)d_in[6];
  const float* wqw    = (const float*)d_in[7];
  const float* wqb    = (const float*)d_in[8];
  const float* wkw    = (const float*)d_in[9];
  const float* wkb    = (const float*)d_in[10];
  const float* wvw    = (const float*)d_in[11];
  const float* wvb    = (const float*)d_in[12];
  const float* wow    = (const float*)d_in[13];
  const float* wob    = (const float*)d_in[14];
  const float* W1in   = (const float*)d_in[15];
  const float* b1in   = (const float*)d_in[16];
  const float* W2in   = (const float*)d_in[17];
  const float* b2in   = (const float*)d_in[18];
  const float* tnw    = (const float*)d_in[19];
  const float* tnb    = (const float*)d_in[20];
  const float* lrw    = (const float*)d_in[21];
  const float* lrb    = (const float*)d_in[22];
  const float* pnw    = (const float*)d_in[23];
  const float* pnb    = (const float*)d_in[24];
  const float* galpha = (const float*)d_in[25];
  float* outp = (float*)d_out;
  char* ws = (char*)d_ws;
  const size_t MB = (size_t)1<<20;
  // f32 buffers
  float* bq  = (float*)(ws + 0*MB);       // TTT proj q (L5->L7)
  float* bk  = (float*)(ws + 16*MB);
  float* bv  = (float*)(ws + 32*MB);
  float* bo  = (float*)(ws + 64*MB);      // tout aliases here
  float* bxb = (float*)(ws + 80*MB);      // residual stream (L4->L6,L10)
  float* xqt = (float*)(ws + 96*MB);      // scan inputs (L7->L8)
  float* tgtp = (float*)(ws + 112*MB);
  unsigned short* xq_bf  = (unsigned short*)(ws + 128*MB);
  unsigned short* xk_bf  = (unsigned short*)(ws + 136*MB);
  float* etab = (float*)(ws + 144*MB);
  unsigned short* xkTe_bf = (unsigned short*)(ws + 48*MB);   // 48-56MB
  // bf16 weight scratch (56-64MB pocket, free until L8 writes bo at 64MB):
  unsigned short* wc0 = (unsigned short*)(ws + 56*MB);
  unsigned short* wc1 = (unsigned short*)(ws + 58*MB);
  unsigned short* wc2 = (unsigned short*)(ws + 60*MB);
  unsigned short* wc3 = (unsigned short*)(ws + 62*MB);
  // bf16 staging buffers, aliased into regions dead at their lifetime:
  unsigned short* bhh_bf  = (unsigned short*)(ws + 96*MB);   // L1->L2 (xqt written L7)
  unsigned short* bq_bf   = (unsigned short*)(ws + 128*MB);  // L2->L3 (xq_bf written L7)
  unsigned short* bk_bf   = (unsigned short*)(ws + 136*MB);  // L2->L3
  unsigned short* bv_bf   = (unsigned short*)(ws + 80*MB);   // L2->L3 (bxb written L4)
  unsigned short* bo_bf   = (unsigned short*)(ws + 112*MB);  // L3->L4 (tgtp written L7)
  unsigned short* bxb_bf  = (unsigned short*)(ws + 128*MB);  // L4->L5 (bq_bf dead after L3)
  unsigned short* bhh2_bf = (unsigned short*)(ws + 0*MB);    // L9->L10 (bq dead after L7)
  float* tout = bo;

  // W-convert #1: attn weights (awq,awk,awv,awo)
  wcvt_kernel<<<dim3(64,4),256,0,stream>>>(awq,awk,awv,awo, wc0,wc1,wc2,wc3);
  // L1: LN -> bf16 only
  ln_kernel<<<4096,256,0,stream>>>(x_in, ln1w, ln1b, nullptr, bhh_bf);
  // L2: fused attn-QKV gemm (bf16 outs only)
  gemm_kernel<<<dim3(24,32),256,0,stream>>>(bhh_bf, wc0,wc1,wc2,
      nullptr,nullptr,nullptr, nullptr, nullptr,
      nullptr,nullptr,nullptr, bq_bf,bk_bf,bv_bf);
  // L3: attention (bf16 in, bf16 out only)
  attn_kernel<<<1024,256,0,stream>>>(bq_bf,bk_bf,bv_bf, nullptr, bo_bf);
  // L4: wo gemm + residual -> bxb f32 + bf16
  gemm_kernel<<<dim3(8,32),256,0,stream>>>(bo_bf, wc3,wc3,wc3,
      nullptr,nullptr,nullptr, x_in, nullptr,
      bxb,bxb,bxb, bxb_bf,bxb_bf,bxb_bf);
  // W-convert #2: TTT weights (wqw,wkw,wvw,wow)
  wcvt_kernel<<<dim3(64,4),256,0,stream>>>(wqw,wkw,wvw,wow, wc0,wc1,wc2,wc3);
  // L5: fused TTT-QKV gemm (f32 outs for xqkv)
  gemm_kernel<<<dim3(24,32),256,0,stream>>>(bxb_bf, wc0,wc1,wc2,
      wqb,wkb,wvb, nullptr, nullptr,
      bq,bk,bv, nullptr,nullptr,nullptr);
  // L6: eta
  eta_kernel<<<1024,256,0,stream>>>(bxb, lrw, lrb, etab);
  // L7: xqkv staging
  xqkv_kernel<<<16384,256,0,stream>>>(bq,bk,bv,tnw,tnb,etab,xqt,tgtp,xq_bf,xk_bf,xkTe_bf);
  // L8: TTT scan (8 waves, 2/EU)
  scan_kernel<<<64,512,0,stream>>>(xqt,tgtp,xq_bf,xk_bf,xkTe_bf,etab,W1in,b1in,W2in,b2in,tnw,tnb,tout);
  // L9: post-scan LN -> bf16 only
  ln_kernel<<<4096,256,0,stream>>>(tout, pnw, pnb, nullptr, bhh2_bf);
  // L10: final gemm with gate + residual
  gemm_kernel<<<dim3(8,32),256,0,stream>>>(bhh2_bf, wc3,wc3,wc3,
      wob,wob,wob, bxb, galpha,
      outp,outp,outp, nullptr,nullptr,nullptr);
}

// Round 14
// 901.308 us; speedup vs baseline: 1.0310x; 1.0078x over previous
//
#include <hip/hip_runtime.h>

// Shapes (fixed): B=4 S=1024 D=1024 H=16 HD=64 C=64 NC=16 DFF=256
typedef short v8s __attribute__((ext_vector_type(8)));
typedef short v4s __attribute__((ext_vector_type(4)));
typedef float v4f __attribute__((ext_vector_type(4)));

__device__ __forceinline__ float bfu(unsigned short u){ return __uint_as_float(((unsigned)u)<<16); }
__device__ __forceinline__ unsigned short fbf(float f){
  unsigned u = __float_as_uint(f);
  u += 0x7fffu + ((u>>16)&1u);
  return (unsigned short)(u>>16);
}
__device__ __forceinline__ float wsum(float v){
  #pragma unroll
  for (int off=32; off>0; off>>=1) v += __shfl_xor(v, off, 64);
  return v;
}
__device__ __forceinline__ float clampv(float x){ return fminf(fmaxf(x, -1e8f), 1e8f); }
__device__ __forceinline__ float tanh_f(float x){
  x = fminf(fmaxf(x, -15.f), 15.f);
  float e = __expf(2.f*x);
  return (e-1.f)/(e+1.f);
}
__device__ __forceinline__ float gelu_f(float x){
  float t = tanh_f(0.79788456f*(x + 0.044715f*x*x*x));
  return 0.5f*x*(1.f+t);
}
__device__ __forceinline__ float gelu_bwd_f(float x){
  float t = tanh_f(0.79788456f*(x + 0.044715f*x*x*x));
  return 0.5f*x*(1.f-t*t)*(0.79788456f + 0.1070322243f*x*x) + 0.5f*(1.f+t);
}
__device__ __forceinline__ v8s ld8(const unsigned short* p){
  v4s lo = *(const v4s*)p, hi = *(const v4s*)(p+4);
  v8s r;
  r[0]=lo[0];r[1]=lo[1];r[2]=lo[2];r[3]=lo[3];
  r[4]=hi[0];r[5]=hi[1];r[6]=hi[2];r[7]=hi[3];
  return r;
}

// ---------------- f32 -> bf16 weight conversion, 4 matrices per launch ----------------
__global__ __launch_bounds__(256) void wcvt_kernel(
    const float* __restrict__ s0, const float* __restrict__ s1,
    const float* __restrict__ s2, const float* __restrict__ s3,
    unsigned short* __restrict__ d0, unsigned short* __restrict__ d1,
    unsigned short* __restrict__ d2, unsigned short* __restrict__ d3)
{
  int y = blockIdx.y;
  const float* s = y==0?s0:(y==1?s1:(y==2?s2:s3));
  unsigned short* d = y==0?d0:(y==1?d1:(y==2?d2:d3));
  int tid = blockIdx.x*256 + threadIdx.x;   // 16384 threads
  #pragma unroll 4
  for (int i=0;i<16;i++){
    size_t o = (size_t)i*65536 + (size_t)tid*4;
    float4 v = *(const float4*)&s[o];
    v4s p;
    p[0]=(short)fbf(v.x); p[1]=(short)fbf(v.y); p[2]=(short)fbf(v.z); p[3]=(short)fbf(v.w);
    *(v4s*)&d[o] = p;
  }
}

// ---------------- LayerNorm over D=1024, one block per row; optional f32/bf16 outs ----------------
__global__ __launch_bounds__(256) void ln_kernel(
    const float* __restrict__ X, const float* __restrict__ g,
    const float* __restrict__ bta, float* __restrict__ out,
    unsigned short* __restrict__ outbf)
{
  __shared__ float red[4];
  int row = blockIdx.x, t = threadIdx.x;
  const float* xr = X + (size_t)row*1024;
  float v[4];
  #pragma unroll
  for (int i=0;i<4;i++) v[i] = xr[t + i*256];
  float s = v[0]+v[1]+v[2]+v[3];
  s = wsum(s);
  if ((t&63)==0) red[t>>6]=s;
  __syncthreads();
  float mu = (red[0]+red[1]+red[2]+red[3])*(1.f/1024.f);
  float q=0.f;
  #pragma unroll
  for (int i=0;i<4;i++){ float dd=v[i]-mu; q+=dd*dd; }
  q = wsum(q);
  __syncthreads();
  if ((t&63)==0) red[t>>6]=q;
  __syncthreads();
  float var = (red[0]+red[1]+red[2]+red[3])*(1.f/1024.f);
  float rs = rsqrtf(var+1e-6f);
  #pragma unroll
  for (int i=0;i<4;i++){
    int c = t+i*256;
    float vv = (v[i]-mu)*rs*g[c] + bta[c];
    if (out)   out[(size_t)row*1024+c] = vv;
    if (outbf) outbf[(size_t)row*1024+c] = fbf(vv);
  }
}

// ---- MFMA GEMM (bf16 A, bf16 pre-converted weights), optionally 3-way fused along N.
// global_load_lds(16B) staging into linear [128][64] LDS with XOR swizzle; low VGPR
// -> __launch_bounds__(256,3): 3 blocks/CU so the 768-block fused launches are fully
// co-resident (no tail wave).
__global__ __launch_bounds__(256, 3) void gemm_kernel(
    const unsigned short* __restrict__ A_bf,
    const unsigned short* __restrict__ B0, const unsigned short* __restrict__ B1, const unsigned short* __restrict__ B2,
    const float* __restrict__ bias0, const float* __restrict__ bias1, const float* __restrict__ bias2,
    const float* __restrict__ res, const float* __restrict__ gate,
    float* __restrict__ out0, float* __restrict__ out1, float* __restrict__ out2,
    unsigned short* __restrict__ obf0, unsigned short* __restrict__ obf1, unsigned short* __restrict__ obf2)
{
  __shared__ __attribute__((aligned(16))) unsigned short a_lds[128*64];
  __shared__ __attribute__((aligned(16))) unsigned short b_lds[128*64];
  int t=threadIdx.x, w=t>>6, lane=t&63;
  int widx = blockIdx.x>>3;
  const unsigned short* Bw = widx==0?B0:(widx==1?B1:B2);
  const float* bias = widx==0?bias0:(widx==1?bias1:bias2);
  float* out        = widx==0?out0:(widx==1?out1:out2);
  unsigned short* obf = widx==0?obf0:(widx==1?obf1:obf2);
  int gm = blockIdx.y*128, gn = (blockIdx.x&7)*128;
  int wm=(w>>1)*64, wn=(w&1)*64, lr=lane&15;
  int rl = lane>>3, j0 = lane&7;          // staging: row-in-chunk, 16B-chunk index
  int qb = (lane>>4)*16;                  // read: byte offset of k-quad within 64B half
  v4f acc[4][4];
  #pragma unroll
  for (int i=0;i<4;i++)
    #pragma unroll
    for (int j=0;j<4;j++){ v4f z={0.f,0.f,0.f,0.f}; acc[i][j]=z; }
  for (int kk=0; kk<1024; kk+=64){
    __syncthreads();
    #pragma unroll
    for (int c=0;c<4;c++){
      int r = w*32 + c*8 + rl;                       // LDS row 0..127
      int js = (j0 ^ (r&7))*16;                      // swizzled source byte-in-row
      const char* ga = (const char*)A_bf + ((size_t)(gm+r)*1024 + kk)*2 + js;
      const char* gb = (const char*)Bw  + ((size_t)(gn+r)*1024 + kk)*2 + js;
      __builtin_amdgcn_global_load_lds(
          (const __attribute__((address_space(1))) void*)ga,
          (__attribute__((address_space(3))) void*)&a_lds[(w*32+c*8)*64], 16, 0, 0);
      __builtin_amdgcn_global_load_lds(
          (const __attribute__((address_space(1))) void*)gb,
          (__attribute__((address_space(3))) void*)&b_lds[(w*32+c*8)*64], 16, 0, 0);
    }
    __syncthreads();
    #pragma unroll
    for (int k2=0;k2<2;k2++){
      v8s af[4], bfr[4];
      #pragma unroll
      for (int i=0;i<4;i++){
        int R = wm+i*16+lr;
        int byt = (k2*64 + qb) ^ ((R&7)<<4);
        af[i] = ld8((const unsigned short*)((const char*)&a_lds[R*64] + byt));
      }
      #pragma unroll
      for (int j=0;j<4;j++){
        int R = wn+j*16+lr;
        int byt = (k2*64 + qb) ^ ((R&7)<<4);
        bfr[j] = ld8((const unsigned short*)((const char*)&b_lds[R*64] + byt));
      }
      #pragma unroll
      for (int i=0;i<4;i++)
        #pragma unroll
        for (int j=0;j<4;j++)
          acc[i][j] = __builtin_amdgcn_mfma_f32_16x16x32_bf16(af[i], bfr[j], acc[i][j], 0,0,0);
    }
  }
  int quad = lane>>4;
  #pragma unroll
  for (int j=0;j<4;j++){
    int gc = gn + wn + j*16 + lr;
    float bval = bias ? bias[gc] : 0.f;
    float gval = gate ? tanh_f(gate[gc]) : 1.f;
    #pragma unroll
    for (int i=0;i<4;i++){
      #pragma unroll
      for (int r=0;r<4;r++){
        int grow = gm + wm + i*16 + quad*4 + r;
        float v = (acc[i][j][r] + bval)*gval;
        if (res) v += res[(size_t)grow*1024 + gc];
        size_t oi = (size_t)grow*1024 + gc;
        if (out) out[oi] = v;
        if (obf) obf[oi] = fbf(v);
      }
    }
  }
}

// ---------------- MFMA flash attention (bf16 in), block = (b,h,q-tile of 64) ----------------
// (256,4): 4 blocks/CU (LDS 4x34.8=139KB, VGPR ~60 <= 128) -> all 1024 blocks
// co-resident; causal work imbalance (qt=0..15) absorbed by the CU scheduler.
__global__ __launch_bounds__(256, 4) void attn_kernel(
    const unsigned short* __restrict__ Q, const unsigned short* __restrict__ K,
    const unsigned short* __restrict__ V, float* __restrict__ O,
    unsigned short* __restrict__ Obf)
{
  __shared__ __attribute__((aligned(16))) unsigned short q_l[64*68];
  __shared__ __attribute__((aligned(16))) unsigned short k_l[64*68];
  __shared__ __attribute__((aligned(16))) unsigned short vt_l[64*68]; // V^T [d][j]
  __shared__ __attribute__((aligned(16))) unsigned short p_l[64*68];
  int t=threadIdx.x, w=t>>6, lane=t&63, q=lane>>4, l16=lane&15;
  int qt = blockIdx.x & 15, bh = blockIdx.x >> 4;
  int b = bh >> 4, h = bh & 15;
  const size_t base = ((size_t)b*1024)*1024 + (size_t)h*64;
  #pragma unroll
  for (int pass=0;pass<4;pass++){
    int slot=t+pass*256, row=slot>>4, c4=(slot&15)*4;
    v4s qv = *(const v4s*)&Q[base + (size_t)(qt*64+row)*1024 + c4];
    *(v4s*)&q_l[row*68+c4]=qv;
  }
  float mi[4], li[4];
  v4f o[4];
  #pragma unroll
  for (int r=0;r<4;r++){ mi[r]=-1e30f; li[r]=0.f; }
  #pragma unroll
  for (int dtn=0;dtn<4;dtn++){ v4f z={0.f,0.f,0.f,0.f}; o[dtn]=z; }
  for (int kt=0; kt<=qt; kt++){
    __syncthreads();
    #pragma unroll
    for (int pass=0;pass<4;pass++){
      int slot=t+pass*256, row=slot>>4, c4=(slot&15)*4;
      v4s kv = *(const v4s*)&K[base + (size_t)(kt*64+row)*1024 + c4];
      *(v4s*)&k_l[row*68+c4]=kv;
      v4s vv = *(const v4s*)&V[base + (size_t)(kt*64+row)*1024 + c4];
      vt_l[(c4+0)*68+row]=(unsigned short)vv[0];
      vt_l[(c4+1)*68+row]=(unsigned short)vv[1];
      vt_l[(c4+2)*68+row]=(unsigned short)vv[2];
      vt_l[(c4+3)*68+row]=(unsigned short)vv[3];
    }
    __syncthreads();
    // S = Q@K^T (wave rows w*16..+15)
    v4f s[4];
    #pragma unroll
    for (int nt=0;nt<4;nt++){ v4f z={0.f,0.f,0.f,0.f}; s[nt]=z; }
    #pragma unroll
    for (int k2=0;k2<2;k2++){
      v8s af = ld8(&q_l[(w*16+l16)*68 + k2*32+q*8]);
      #pragma unroll
      for (int nt=0;nt<4;nt++){
        v8s bf = ld8(&k_l[(nt*16+l16)*68 + k2*32+q*8]);
        s[nt] = __builtin_amdgcn_mfma_f32_16x16x32_bf16(af, bf, s[nt], 0,0,0);
      }
    }
    bool diag = (kt==qt);
    #pragma unroll
    for (int r=0;r<4;r++){
      int row_l = w*16+q*4+r;
      float mx=-1e30f;
      #pragma unroll
      for (int nt=0;nt<4;nt++){
        int col=nt*16+l16;
        float sv = s[nt][r]*0.125f;
        if (diag && col>row_l) sv=-1e30f;
        s[nt][r]=sv; mx=fmaxf(mx,sv);
      }
      #pragma unroll
      for (int off=1;off<16;off<<=1) mx=fmaxf(mx,__shfl_xor(mx,off,16));
      float mnew=fmaxf(mi[r],mx);
      float aexp=__expf(mi[r]-mnew);
      float ps=0.f;
      #pragma unroll
      for (int nt=0;nt<4;nt++){
        float p=__expf(s[nt][r]-mnew);
        s[nt][r]=p; ps+=p;
      }
      #pragma unroll
      for (int off=1;off<16;off<<=1) ps+=__shfl_xor(ps,off,16);
      li[r]=li[r]*aexp+ps; mi[r]=mnew;
      #pragma unroll
      for (int dtn=0;dtn<4;dtn++) o[dtn][r]*=aexp;
      #pragma unroll
      for (int nt=0;nt<4;nt++) p_l[row_l*68 + nt*16+l16]=fbf(s[nt][r]);
    }
    __syncthreads();
    // O += P@V
    #pragma unroll
    for (int k2=0;k2<2;k2++){
      v8s af = ld8(&p_l[(w*16+l16)*68 + k2*32+q*8]);
      #pragma unroll
      for (int dtn=0;dtn<4;dtn++){
        v8s bf = ld8(&vt_l[(dtn*16+l16)*68 + k2*32+q*8]);
        o[dtn] = __builtin_amdgcn_mfma_f32_16x16x32_bf16(af, bf, o[dtn], 0,0,0);
      }
    }
  }
  #pragma unroll
  for (int dtn=0;dtn<4;dtn++)
    #pragma unroll
    for (int r=0;r<4;r++){
      float vv = o[dtn][r]/li[r];
      size_t oi = base + (size_t)(qt*64+w*16+q*4+r)*1024 + dtn*16+l16;
      if (O)   O[oi] = vv;
      if (Obf) Obf[oi] = fbf(vv);
    }
}

// ------- XQ/XK normalize + target fuse; write TTT layouts. wave = (b,s,h) -------
__global__ __launch_bounds__(256) void xqkv_kernel(
    const float* __restrict__ XQ, const float* __restrict__ XK,
    const float* __restrict__ XV, const float* __restrict__ nw,
    const float* __restrict__ nb, const float* __restrict__ eta,
    float* __restrict__ xqt, float* __restrict__ tgtp,
    unsigned short* __restrict__ xq_bf, unsigned short* __restrict__ xk_bf,
    unsigned short* __restrict__ xkTe_bf)
{
  int gw = (int)((blockIdx.x*256 + threadIdx.x)>>6);
  int lane = threadIdx.x & 63;
  int h = gw & 15, s = (gw>>4)&1023, b = gw>>14;
  size_t src = ((size_t)(b*1024+s))*1024 + h*64 + lane;
  float xq = XQ[src], xk = XK[src], xv = XV[src];
  float nq = sqrtf(wsum(xq*xq));
  float nk = sqrtf(wsum(xk*xk));
  float xqn = xq / fmaxf(nq, 1e-12f);
  float xkn = xk / fmaxf(nk, 1e-12f);
  float mu = wsum(xv)*(1.f/64.f);
  float xm = xv-mu;
  float var = wsum(xm*xm)*(1.f/64.f);
  float xvh = xm*rsqrtf(var+1e-6f);
  float tg = nw[h*64+lane]*xvh + nb[h*64+lane];   // xvn - xkn exactly
  float et = eta[((size_t)(b*16+h))*1024 + s];
  size_t dst = ((size_t)(b*16+h)*1024 + s)*64 + lane;
  xq_bf[dst]=fbf(xqn); xk_bf[dst]=fbf(xkn);
  xkTe_bf[((size_t)(b*16+h)*64 + lane)*1024 + s] = fbf(-et*xkn);
  int n_ = s>>6, row = s&63;
  int wv = row>>4, qq = (row>>2)&3, rr = row&3;
  int nt_ = lane>>4, l16_ = lane&15;
  int tt = wv*64 + qq*16 + l16_;
  size_t dst2 = (size_t)(b*16+h)*65536 + (size_t)n_*4096 + (size_t)tt*16 + nt_*4 + rr;
  xqt[dst2]=xqn; tgtp[dst2]=tg;
}

// ------- eta[b,h,s] = sigmoid(x[b,s,:]·lr_w[h,:] + lr_b[h]) / 64. wave = (b,s) -------
__global__ __launch_bounds__(256) void eta_kernel(
    const float* __restrict__ Xb, const float* __restrict__ lrw,
    const float* __restrict__ lrb, float* __restrict__ eta)
{
  int gw = (int)((blockIdx.x*256 + threadIdx.x)>>6);
  int lane = threadIdx.x & 63;
  int s = gw & 1023, b = gw >> 10;
  const float* xrow = Xb + ((size_t)(b*1024+s))*1024;
  float xr[16];
  #pragma unroll
  for (int i=0;i<16;i++) xr[i] = xrow[i*64+lane];
  #pragma unroll 1
  for (int h=0;h<16;h++){
    const float* wr = lrw + h*1024;
    float acc=0.f;
    #pragma unroll
    for (int i=0;i<16;i++) acc += xr[i]*wr[i*64+lane];
    acc = wsum(acc);
    if (lane==h){
      float vv = acc + lrb[h];
      float sg = 1.f/(1.f+__expf(-vv));
      eta[((size_t)(b*16+h))*1024 + s] = sg*(1.f/64.f);
    }
  }
}

// ---------------- TTT scan (MFMA, LDS-resident), 512 threads = 8 waves ----------------
// Frozen at round-8's measured-best form (489-493us): register-diet gbp/x2bp,
// two-barrier LN2, per-phase loads, ln_scr stride 8.
__global__ __launch_bounds__(512, 2) __attribute__((amdgpu_waves_per_eu(2, 2)))
void scan_kernel(
    const float* __restrict__ xqt, const float* __restrict__ tgtp,
    const unsigned short* __restrict__ xq_bf, const unsigned short* __restrict__ xk_bf,
    const unsigned short* __restrict__ xkTe_bf, const float* __restrict__ eta,
    const float* __restrict__ W1in, const float* __restrict__ b1in,
    const float* __restrict__ W2in, const float* __restrict__ b2in,
    const float* __restrict__ nw, const float* __restrict__ nb,
    float* __restrict__ tout)
{
  __shared__ __attribute__((aligned(16))) unsigned short W1t[256*68];  // W1^T [n][k]
  __shared__ __attribute__((aligned(16))) unsigned short W2T[64*260];  // W2^T [d][k]
  __shared__ __attribute__((aligned(16))) unsigned short X2s[64*260];  // X2 [m][n]
  __shared__ __attribute__((aligned(16))) unsigned short GXu[256*68];  // GZ1t [n][j] / X2b [m][n](260)
  __shared__ __attribute__((aligned(16))) unsigned short GZ2t[64*68];  // gZ2^T [d][j]
  __shared__ __attribute__((aligned(16))) unsigned short AMs[64*68];   // -tril(eta*(A+1)) [m][j]
  __shared__ float ln_scr[64*8];
  __shared__ float eta_s[64], b1_s[256], b2_s[64], nw_s[64], nb_s[64];

  const int t=threadIdx.x, w=t>>6, lane=t&63, q=lane>>4, l16=lane&15;
  const int bh=blockIdx.x, b=bh>>4, h=bh&15;
  const int mt=w>>1, half=w&1, nh=half*8, nh4=half*2;
  const float* xq_g  = xqt  + (size_t)bh*65536;
  const float* tgt_g = tgtp + (size_t)bh*65536;
  const unsigned short* xqb_g = xq_bf  + (size_t)bh*65536;
  const unsigned short* xkb_g = xk_bf  + (size_t)bh*65536;
  const unsigned short* xkT_g = xkTe_bf + (size_t)bh*65536;
  const float* eta_g = eta + (size_t)bh*1024;

  // W1 masters (C-frag): rows mt*16+q*4+r, cols (nh+nt)*16+l16
  v4f w1r[8];
  #pragma unroll
  for (int nt=0;nt<8;nt++){
    int col=(nh+nt)*16+l16;
    #pragma unroll
    for (int r=0;r<4;r++) w1r[nt][r] = W1in[h*16384 + (mt*16+q*4+r)*256 + col];
  }
  // W2 masters: rows (w*2+mi)*16+q*4+r, cols nt*16+l16
  v4f w2r[2][4];
  #pragma unroll
  for (int mi=0;mi<2;mi++)
    #pragma unroll
    for (int nt=0;nt<4;nt++){
      int col=nt*16+l16;
      #pragma unroll
      for (int r=0;r<4;r++) w2r[mi][nt][r] = W2in[h*16384 + ((w*2+mi)*16+q*4+r)*64 + col];
    }
  if (t<256) b1_s[t]=b1in[h*256+t];
  if (t<64){ b2_s[t]=b2in[h*64+t]; nw_s[t]=nw[h*64+t]; nb_s[t]=nb[h*64+t]; }

  float bacc=0.f, bacc2=0.f;   // deferred bias updates

  for (int n=0;n<16;n++){
    // prefetch this step's A-fragments (global, safe pre-barrier)
    v8s xkf[2], xqf[2];
    #pragma unroll
    for (int kt=0;kt<2;kt++){
      xkf[kt] = ld8(&xkb_g[(size_t)n*4096 + (mt*16+l16)*64 + kt*32+q*8]);
      xqf[kt] = ld8(&xqb_g[(size_t)n*4096 + (mt*16+l16)*64 + kt*32+q*8]);
    }
    __syncthreads();                                        // B1: prev-step readers done
    if (t<256) b1_s[t] -= bacc;
    if (t<64){ b2_s[t] -= bacc2; eta_s[t]=eta_g[n*64+t]; }
    // ---- stage bf16 W copies (transposed) ----
    #pragma unroll
    for (int nt=0;nt<8;nt++){
      int col=(nh+nt)*16+l16;
      #pragma unroll
      for (int pr=0;pr<2;pr++){
        unsigned lo=fbf(w1r[nt][pr*2]), hi=fbf(w1r[nt][pr*2+1]);
        *(unsigned*)&W1t[col*68 + mt*16+q*4 + pr*2] = lo | (hi<<16);
      }
    }
    #pragma unroll
    for (int mi=0;mi<2;mi++)
      #pragma unroll
      for (int nt=0;nt<4;nt++){
        int col=nt*16+l16;
        #pragma unroll
        for (int pr=0;pr<2;pr++){
          unsigned lo=fbf(w2r[mi][nt][pr*2]), hi=fbf(w2r[mi][nt][pr*2+1]);
          *(unsigned*)&W2T[col*260 + (w*2+mi)*16+q*4 + pr*2] = lo | (hi<<16);
        }
      }
    __syncthreads();                                        // B2: staging visible

    // ---- P1: Z1 = xk@W1 + b1; X2 -> X2s; gelu' packed bf16 -> gbp. A4 -> AMs. ----
    unsigned gbp[16];
    {
      v4f a1[8];
      #pragma unroll
      for (int i=0;i<8;i++){ v4f z={0.f,0.f,0.f,0.f}; a1[i]=z; }
      #pragma unroll
      for (int kt=0;kt<2;kt++){
        #pragma unroll
        for (int nt=0;nt<8;nt++){
          v8s bf = ld8(&W1t[((nh+nt)*16+l16)*68 + kt*32+q*8]);
          a1[nt] = __builtin_amdgcn_mfma_f32_16x16x32_bf16(xkf[kt], bf, a1[nt], 0,0,0);
        }
      }
      #pragma unroll
      for (int nt=0;nt<8;nt++){
        int col=(nh+nt)*16+l16; float bb=b1_s[col];
        float zz[4];
        #pragma unroll
        for (int r=0;r<4;r++){
          float z=clampv(a1[nt][r]+bb); zz[r]=z;
          X2s[(mt*16+q*4+r)*260+col]=fbf(clampv(gelu_f(z)));
        }
        #pragma unroll
        for (int pr=0;pr<2;pr++)
          gbp[nt*2+pr] = (unsigned)fbf(gelu_bwd_f(zz[pr*2+0]))
                       | ((unsigned)fbf(gelu_bwd_f(zz[pr*2+1]))<<16);
      }
    }
    {
      v4f a4[2];
      #pragma unroll
      for (int i=0;i<2;i++){ v4f z={0.f,0.f,0.f,0.f}; a4[i]=z; }
      #pragma unroll
      for (int kt=0;kt<2;kt++){
        #pragma unroll
        for (int nt=0;nt<2;nt++){
          v8s bf = ld8(&xkb_g[(size_t)n*4096 + ((nh4+nt)*16+l16)*64 + kt*32+q*8]);
          a4[nt] = __builtin_amdgcn_mfma_f32_16x16x32_bf16(xqf[kt], bf, a4[nt], 0,0,0);
        }
      }
      #pragma unroll
      for (int nt=0;nt<2;nt++){
        int col=(nh4+nt)*16+l16;
        float ec=eta_s[col];
        #pragma unroll
        for (int r=0;r<4;r++){
          int row=mt*16+q*4+r;
          AMs[row*68+col] = (col<=row) ? fbf(-ec*(a4[nt][r]+1.f)) : (unsigned short)0;
        }
      }
    }

    // ---- P2: Z2 = X2@W2 + b2 ; LN2 (cross-half via ln_scr) -> GZ2t ----
    {
      const float* tc = tgt_g + (size_t)n*4096 + (size_t)(mt*64+q*16+l16)*16 + nh4*4;
      float4 ta=*(const float4*)tc, tb=*(const float4*)(tc+4);
      float tgs[8]={ta.x,ta.y,ta.z,ta.w,tb.x,tb.y,tb.z,tb.w};
      v4f a2[2];
      #pragma unroll
      for (int i=0;i<2;i++){ v4f z={0.f,0.f,0.f,0.f}; a2[i]=z; }
      #pragma unroll
      for (int kt=0;kt<8;kt++){
        v8s af = ld8(&X2s[(mt*16+l16)*260 + kt*32+q*8]);
        #pragma unroll
        for (int nt=0;nt<2;nt++){
          v8s bf = ld8(&W2T[((nh4+nt)*16+l16)*260 + kt*32+q*8]);
          a2[nt] = __builtin_amdgcn_mfma_f32_16x16x32_bf16(af, bf, a2[nt], 0,0,0);
        }
      }
      float z2[2][4];
      #pragma unroll
      for (int nt=0;nt<2;nt++){
        float bb=b2_s[(nh4+nt)*16+l16];
        #pragma unroll
        for (int r=0;r<4;r++) z2[nt][r]=clampv(a2[nt][r]+bb);
      }
      #pragma unroll
      for (int r=0;r<4;r++){
        float s1v=z2[0][r]+z2[1][r];
        float s2v=z2[0][r]*z2[0][r]+z2[1][r]*z2[1][r];
        #pragma unroll
        for (int off=1;off<16;off<<=1){ s1v+=__shfl_xor(s1v,off,16); s2v+=__shfl_xor(s2v,off,16); }
        if (l16==0){ int row=mt*16+q*4+r; ln_scr[row*8+half]=s1v; ln_scr[row*8+2+half]=s2v; }
      }
      __syncthreads();                                      // B3
      float muv[4], istd[4];
      #pragma unroll
      for (int r=0;r<4;r++){
        int row=mt*16+q*4+r;
        float S1=ln_scr[row*8+0]+ln_scr[row*8+1];
        float S2=ln_scr[row*8+2]+ln_scr[row*8+3];
        float mu=S1*(1.f/64.f);
        float var=fmaxf(S2*(1.f/64.f)-mu*mu, 0.f);
        muv[r]=mu; istd[r]=rsqrtf(var+1e-6f);
      }
      float xh[2][4], gh[2][4];
      #pragma unroll
      for (int nt=0;nt<2;nt++){
        int col=(nh4+nt)*16+l16;
        float gw_=nw_s[col], gb_=nb_s[col];
        #pragma unroll
        for (int r=0;r<4;r++){
          float x_=(z2[nt][r]-muv[r])*istd[r];
          float tgv = tgs[nt*4+r];
          xh[nt][r]=x_;
          gh[nt][r]=(gw_*x_+gb_-tgv)*gw_;
        }
      }
      #pragma unroll
      for (int r=0;r<4;r++){
        float t1=gh[0][r]+gh[1][r];
        float t2=gh[0][r]*xh[0][r]+gh[1][r]*xh[1][r];
        #pragma unroll
        for (int off=1;off<16;off<<=1){ t1+=__shfl_xor(t1,off,16); t2+=__shfl_xor(t2,off,16); }
        if (l16==0){ int row=mt*16+q*4+r; ln_scr[row*8+4+half]=t1; ln_scr[row*8+6+half]=t2; }
      }
      __syncthreads();                                      // B4
      #pragma unroll
      for (int nt=0;nt<2;nt++){
        int col=(nh4+nt)*16+l16;
        #pragma unroll
        for (int pr=0;pr<2;pr++){
          unsigned pk[2];
          #pragma unroll
          for (int k2=0;k2<2;k2++){
            int r=pr*2+k2;
            int row=mt*16+q*4+r;
            float G1s=ln_scr[row*8+4]+ln_scr[row*8+5];
            float G2s=ln_scr[row*8+6]+ln_scr[row*8+7];
            float gz=(64.f*gh[nt][r]-G1s-xh[nt][r]*G2s)*istd[r]*(1.f/64.f);
            pk[k2]=fbf(clampv(gz));
          }
          *(unsigned*)&GZ2t[col*68 + mt*16+q*4 + pr*2] = pk[0] | (pk[1]<<16);
        }
      }
    }
    __syncthreads();                                        // B5: GZ2t (both halves) visible

    // ---- P3: gZ1 = (gZ2@W2^T) * gelu'(Z1) -> GZ1t [n][j] ----
    {
      v4f a3[8];
      #pragma unroll
      for (int i=0;i<8;i++){ v4f z={0.f,0.f,0.f,0.f}; a3[i]=z; }
      #pragma unroll
      for (int kt=0;kt<2;kt++){
        v8s af;
        #pragma unroll
        for (int j=0;j<8;j++) af[j]=(short)GZ2t[(kt*32+q*8+j)*68 + mt*16+l16];
        #pragma unroll
        for (int nt=0;nt<8;nt++){
          int nb0=(nh+nt)*16+l16;
          v8s bf;
          #pragma unroll
          for (int j=0;j<8;j++) bf[j]=(short)W2T[(kt*32+q*8+j)*260 + nb0];
          a3[nt] = __builtin_amdgcn_mfma_f32_16x16x32_bf16(af, bf, a3[nt], 0,0,0);
        }
      }
      #pragma unroll
      for (int nt=0;nt<8;nt++){
        int col=(nh+nt)*16+l16;
        #pragma unroll
        for (int pr=0;pr<2;pr++){
          float d0=bfu((unsigned short)(gbp[nt*2+pr]&0xffffu));
          float d1=bfu((unsigned short)(gbp[nt*2+pr]>>16));
          float g0=clampv(a3[nt][pr*2+0]*d0);
          float g1=clampv(a3[nt][pr*2+1]*d1);
          unsigned lo=fbf(g0), hi=fbf(g1);
          *(unsigned*)&GXu[col*68 + mt*16+q*4 + pr*2] = lo | (hi<<16);
        }
      }
    }
    __syncthreads();                                        // B6: GZ1t visible

    // ---- P5: Z1b = xq@W1 + AMs@gZ1 + b1 ; H1 in-place: W1 += (-eta xk)^T @ gZ1 ;
    //      then compress X2b = fbf(gelu(Z1b+b1)) into x2bp BEFORE the barrier. ----
    unsigned x2bp[16];
    {
      float p0=0.f,p1=0.f,p2=0.f,p3=0.f;
      if (t<256){
        #pragma unroll
        for (int j4=0;j4<16;j4++){
          v4s v=*(const v4s*)&GXu[t*68+j4*4];
          p0 += eta_s[j4*4+0]*bfu((unsigned short)v[0]);
          p1 += eta_s[j4*4+1]*bfu((unsigned short)v[1]);
          p2 += eta_s[j4*4+2]*bfu((unsigned short)v[2]);
          p3 += eta_s[j4*4+3]*bfu((unsigned short)v[3]);
        }
      }
      bacc=(p0+p1)+(p2+p3);
      v8s xef[2];
      #pragma unroll
      for (int kt=0;kt<2;kt++)
        xef[kt] = ld8(&xkT_g[(size_t)(mt*16+l16)*1024 + n*64 + kt*32+q*8]);
      v4f a5[8];
      #pragma unroll
      for (int i=0;i<8;i++){ v4f z={0.f,0.f,0.f,0.f}; a5[i]=z; }
      #pragma unroll
      for (int kt=0;kt<2;kt++){
        #pragma unroll
        for (int nt=0;nt<8;nt++){
          v8s bf = ld8(&W1t[((nh+nt)*16+l16)*68 + kt*32+q*8]);
          a5[nt] = __builtin_amdgcn_mfma_f32_16x16x32_bf16(xqf[kt], bf, a5[nt], 0,0,0);
        }
      }
      #pragma unroll
      for (int kt=0;kt<2;kt++){
        v8s afA = ld8(&AMs[(mt*16+l16)*68 + kt*32+q*8]);
        #pragma unroll
        for (int nt=0;nt<8;nt++){
          v8s bf = ld8(&GXu[((nh+nt)*16+l16)*68 + kt*32+q*8]);
          a5[nt] = __builtin_amdgcn_mfma_f32_16x16x32_bf16(afA, bf, a5[nt], 0,0,0);
          w1r[nt] = __builtin_amdgcn_mfma_f32_16x16x32_bf16(xef[kt], bf, w1r[nt], 0,0,0);
        }
      }
      #pragma unroll
      for (int nt=0;nt<8;nt++){
        float bb=b1_s[(nh+nt)*16+l16];
        #pragma unroll
        for (int pr=0;pr<2;pr++){
          float z0=clampv(a5[nt][pr*2+0]+bb);
          float z1=clampv(a5[nt][pr*2+1]+bb);
          x2bp[nt*2+pr] = (unsigned)fbf(clampv(gelu_f(z0)))
                        | ((unsigned)fbf(clampv(gelu_f(z1)))<<16);
        }
      }
    }
    __syncthreads();                                        // B7: GXu/AMs reads done

    // ---- X2b (packed) -> GXu row-major [m][n](260) ----
    #pragma unroll
    for (int nt=0;nt<8;nt++){
      int col=(nh+nt)*16+l16;
      #pragma unroll
      for (int pr=0;pr<2;pr++){
        int row0=mt*16+q*4+pr*2;
        GXu[row0*260+col]     = (unsigned short)(x2bp[nt*2+pr]&0xffffu);
        GXu[(row0+1)*260+col] = (unsigned short)(x2bp[nt*2+pr]>>16);
      }
    }
    __syncthreads();                                        // B8: X2b visible

    // ---- P6: AMs = -tril(eta_j*(X2b@X2^T + 1)) ; b2 colsum (deferred) ----
    {
      float p0=0.f,p1=0.f,p2=0.f,p3=0.f;
      if (t<64){
        #pragma unroll
        for (int j4=0;j4<16;j4++){
          v4s v=*(const v4s*)&GZ2t[t*68+j4*4];
          p0 += eta_s[j4*4+0]*bfu((unsigned short)v[0]);
          p1 += eta_s[j4*4+1]*bfu((unsigned short)v[1]);
          p2 += eta_s[j4*4+2]*bfu((unsigned short)v[2]);
          p3 += eta_s[j4*4+3]*bfu((unsigned short)v[3]);
        }
      }
      bacc2=(p0+p1)+(p2+p3);
      v4f a7[2];
      #pragma unroll
      for (int i=0;i<2;i++){ v4f z={0.f,0.f,0.f,0.f}; a7[i]=z; }
      #pragma unroll
      for (int kt=0;kt<8;kt++){
        v8s af = ld8(&GXu[(mt*16+l16)*260 + kt*32+q*8]);   // X2b
        #pragma unroll
        for (int nt=0;nt<2;nt++){
          v8s bf = ld8(&X2s[((nh4+nt)*16+l16)*260 + kt*32+q*8]);
          a7[nt] = __builtin_amdgcn_mfma_f32_16x16x32_bf16(af, bf, a7[nt], 0,0,0);
        }
      }
      #pragma unroll
      for (int nt=0;nt<2;nt++){
        int col=(nh4+nt)*16+l16;
        float ec=eta_s[col];
        #pragma unroll
        for (int r=0;r<4;r++){
          int row=mt*16+q*4+r;
          AMs[row*68+col] = (col<=row) ? fbf(-ec*(a7[nt][r]+1.f)) : (unsigned short)0;
        }
      }
    }
    __syncthreads();                                        // B9: AMs visible

    // ---- P7: Z2b = X2b@W2 + AMs@gZ2 + b2 ; LN7 -> tout ; H2 in-place ----
    {
      const float* xc = xq_g + (size_t)n*4096 + (size_t)(mt*64+q*16+l16)*16 + nh4*4;
      float4 xa=*(const float4*)xc, xb=*(const float4*)(xc+4);
      float xqs[8]={xa.x,xa.y,xa.z,xa.w,xb.x,xb.y,xb.z,xb.w};
      v4f a8[2];
      #pragma unroll
      for (int i=0;i<2;i++){ v4f z={0.f,0.f,0.f,0.f}; a8[i]=z; }
      float b2old[2];
      #pragma unroll
      for (int nt=0;nt<2;nt++) b2old[nt]=b2_s[(nh4+nt)*16+l16];
      #pragma unroll
      for (int kt=0;kt<8;kt++){
        v8s af = ld8(&GXu[(mt*16+l16)*260 + kt*32+q*8]);   // X2b
        #pragma unroll
        for (int nt=0;nt<2;nt++){
          v8s bf = ld8(&W2T[((nh4+nt)*16+l16)*260 + kt*32+q*8]);
          a8[nt] = __builtin_amdgcn_mfma_f32_16x16x32_bf16(af, bf, a8[nt], 0,0,0);
        }
      }
      #pragma unroll
      for (int kt=0;kt<2;kt++){
        v8s afm = ld8(&AMs[(mt*16+l16)*68 + kt*32+q*8]);
        #pragma unroll
        for (int nt=0;nt<2;nt++){
          v8s bf = ld8(&GZ2t[((nh4+nt)*16+l16)*68 + kt*32+q*8]);
          a8[nt] = __builtin_amdgcn_mfma_f32_16x16x32_bf16(afm, bf, a8[nt], 0,0,0);
        }
      }
      float z2b[2][4];
      #pragma unroll
      for (int nt=0;nt<2;nt++)
        #pragma unroll
        for (int r=0;r<4;r++) z2b[nt][r]=clampv(a8[nt][r]+b2old[nt]);
      #pragma unroll
      for (int r=0;r<4;r++){
        float s1v=z2b[0][r]+z2b[1][r];
        float s2v=z2b[0][r]*z2b[0][r]+z2b[1][r]*z2b[1][r];
        #pragma unroll
        for (int off=1;off<16;off<<=1){ s1v+=__shfl_xor(s1v,off,16); s2v+=__shfl_xor(s2v,off,16); }
        if (l16==0){ int row=mt*16+q*4+r; ln_scr[row*8+half]=s1v; ln_scr[row*8+2+half]=s2v; }
      }
      __syncthreads();                                      // B10
      #pragma unroll
      for (int r=0;r<4;r++){
        int row=mt*16+q*4+r;
        float S1=ln_scr[row*8+0]+ln_scr[row*8+1];
        float S2=ln_scr[row*8+2]+ln_scr[row*8+3];
        float mu=S1*(1.f/64.f);
        float var=fmaxf(S2*(1.f/64.f)-mu*mu, 0.f);
        float istd=rsqrtf(var+1e-6f);
        #pragma unroll
        for (int nt=0;nt<2;nt++){
          int col=(nh4+nt)*16+l16;
          float x_=(z2b[nt][r]-mu)*istd;
          float outv = xqs[nt*4+r] + x_*nw_s[col] + nb_s[col];
          tout[((size_t)(b*1024 + n*64 + row))*1024 + h*64 + col] = outv;
        }
      }
      // H2 in-place: W2 += (-eta X2)^T @ gZ2
      #pragma unroll
      for (int kt=0;kt<2;kt++){
        v8s bfs[4];
        #pragma unroll
        for (int nt=0;nt<4;nt++) bfs[nt] = ld8(&GZ2t[(nt*16+l16)*68 + kt*32+q*8]);
        #pragma unroll
        for (int mi=0;mi<2;mi++){
          v8s af;
          #pragma unroll
          for (int j=0;j<8;j++){
            int jj=kt*32+q*8+j;
            af[j]=(short)fbf(-eta_s[jj]*bfu(X2s[jj*260 + (w*2+mi)*16+l16]));
          }
          #pragma unroll
          for (int nt=0;nt<4;nt++)
            w2r[mi][nt] = __builtin_amdgcn_mfma_f32_16x16x32_bf16(af, bfs[nt], w2r[mi][nt], 0,0,0);
        }
      }
    }
  }
}

extern "C" void kernel_launch(void* const* d_in, const int* in_sizes, int n_in,
                              void* d_out, int out_size, void* d_ws, size_t ws_size,
                              hipStream_t stream)
{
  const float* x_in   = (const float*)d_in[0];
  const float* ln1w   = (const float*)d_in[1];
  const float* ln1b   = (const float*)d_in[2];
  const float* awq    = (const float*)d_in[3];
  const float* awk    = (const float*)d_in[4];
  const float* awv    = (const float*)d_in[5];
  const float* awo    = (const float*)d_in[6];
  const float* wqw    = (const float*)d_in[7];
  const float* wqb    = (const float*)d_in[8];
  const float* wkw    = (const float*)d_in[9];
  const float* wkb    = (const float*)d_in[10];
  const float* wvw    = (const float*)d_in[11];
  const float* wvb    = (const float*)d_in[12];
  const float* wow    = (const float*)d_in[13];
  const float* wob    = (const float*)d_in[14];
  const float* W1in   = (const float*)d_in[15];
  const float* b1in   = (const float*)d_in[16];
  const float* W2in   = (const float*)d_in[17];
  const float* b2in   = (const float*)d_in[18];
  const float* tnw    = (const float*)d_in[19];
  const float* tnb    = (const float*)d_in[20];
  const float* lrw    = (const float*)d_in[21];
  const float* lrb    = (const float*)d_in[22];
  const float* pnw    = (const float*)d_in[23];
  const float* pnb    = (const float*)d_in[24];
  const float* galpha = (const float*)d_in[25];
  float* outp = (float*)d_out;
  char* ws = (char*)d_ws;
  const size_t MB = (size_t)1<<20;
  // f32 buffers
  float* bq  = (float*)(ws + 0*MB);       // TTT proj q (L5->L7)
  float* bk  = (float*)(ws + 16*MB);
  float* bv  = (float*)(ws + 32*MB);
  float* bo  = (float*)(ws + 64*MB);      // tout aliases here
  float* bxb = (float*)(ws + 80*MB);      // residual stream (L4->L6,L10)
  float* xqt = (float*)(ws + 96*MB);      // scan inputs (L7->L8)
  float* tgtp = (float*)(ws + 112*MB);
  unsigned short* xq_bf  = (unsigned short*)(ws + 128*MB);
  unsigned short* xk_bf  = (unsigned short*)(ws + 136*MB);
  float* etab = (float*)(ws + 144*MB);
  unsigned short* xkTe_bf = (unsigned short*)(ws + 48*MB);   // 48-56MB
  // bf16 weight scratch (56-64MB pocket, free until L8 writes bo at 64MB):
  unsigned short* wc0 = (unsigned short*)(ws + 56*MB);
  unsigned short* wc1 = (unsigned short*)(ws + 58*MB);
  unsigned short* wc2 = (unsigned short*)(ws + 60*MB);
  unsigned short* wc3 = (unsigned short*)(ws + 62*MB);
  // bf16 staging buffers, aliased into regions dead at their lifetime:
  unsigned short* bhh_bf  = (unsigned short*)(ws + 96*MB);   // L1->L2 (xqt written L7)
  unsigned short* bq_bf   = (unsigned short*)(ws + 128*MB);  // L2->L3 (xq_bf written L7)
  unsigned short* bk_bf   = (unsigned short*)(ws + 136*MB);  // L2->L3
  unsigned short* bv_bf   = (unsigned short*)(ws + 80*MB);   // L2->L3 (bxb written L4)
  unsigned short* bo_bf   = (unsigned short*)(ws + 112*MB);  // L3->L4 (tgtp written L7)
  unsigned short* bxb_bf  = (unsigned short*)(ws + 128*MB);  // L4->L5 (bq_bf dead after L3)
  unsigned short* bhh2_bf = (unsigned short*)(ws + 0*MB);    // L9->L10 (bq dead after L7)
  float* tout = bo;

  // W-convert #1: attn weights (awq,awk,awv,awo)
  wcvt_kernel<<<dim3(64,4),256,0,stream>>>(awq,awk,awv,awo, wc0,wc1,wc2,wc3);
  // L1: LN -> bf16 only
  ln_kernel<<<4096,256,0,stream>>>(x_in, ln1w, ln1b, nullptr, bhh_bf);
  // L2: fused attn-QKV gemm (bf16 outs only)
  gemm_kernel<<<dim3(24,32),256,0,stream>>>(bhh_bf, wc0,wc1,wc2,
      nullptr,nullptr,nullptr, nullptr, nullptr,
      nullptr,nullptr,nullptr, bq_bf,bk_bf,bv_bf);
  // L3: attention (bf16 in, bf16 out only)
  attn_kernel<<<1024,256,0,stream>>>(bq_bf,bk_bf,bv_bf, nullptr, bo_bf);
  // L4: wo gemm + residual -> bxb f32 + bf16
  gemm_kernel<<<dim3(8,32),256,0,stream>>>(bo_bf, wc3,wc3,wc3,
      nullptr,nullptr,nullptr, x_in, nullptr,
      bxb,bxb,bxb, bxb_bf,bxb_bf,bxb_bf);
  // W-convert #2: TTT weights (wqw,wkw,wvw,wow)
  wcvt_kernel<<<dim3(64,4),256,0,stream>>>(wqw,wkw,wvw,wow, wc0,wc1,wc2,wc3);
  // L5: fused TTT-QKV gemm (f32 outs for xqkv)
  gemm_kernel<<<dim3(24,32),256,0,stream>>>(bxb_bf, wc0,wc1,wc2,
      wqb,wkb,wvb, nullptr, nullptr,
      bq,bk,bv, nullptr,nullptr,nullptr);
  // L6: eta
  eta_kernel<<<1024,256,0,stream>>>(bxb, lrw, lrb, etab);
  // L7: xqkv staging
  xqkv_kernel<<<16384,256,0,stream>>>(bq,bk,bv,tnw,tnb,etab,xqt,tgtp,xq_bf,xk_bf,xkTe_bf);
  // L8: TTT scan (8 waves, 2/EU)
  scan_kernel<<<64,512,0,stream>>>(xqt,tgtp,xq_bf,xk_bf,xkTe_bf,etab,W1in,b1in,W2in,b2in,tnw,tnb,tout);
  // L9: post-scan LN -> bf16 only
  ln_kernel<<<4096,256,0,stream>>>(tout, pnw, pnb, nullptr, bhh2_bf);
  // L10: final gemm with gate + residual
  gemm_kernel<<<dim3(8,32),256,0,stream>>>(bhh2_bf, wc3,wc3,wc3,
      wob,wob,wob, bxb, galpha,
      outp,outp,outp, nullptr,nullptr,nullptr);
}